// Round 6
// baseline (533.176 us; speedup 1.0000x reference)
//
#include <hip/hip_runtime.h>
#include <cmath>

typedef __attribute__((ext_vector_type(8))) short bf16x8;
typedef __attribute__((ext_vector_type(8))) _Float16 f16x8;
typedef __attribute__((ext_vector_type(4))) float f32x4;

__device__ inline unsigned short f2bf_rne(float f) {
    unsigned int u = __float_as_uint(f);
    unsigned int r = (u + 0x7FFFu + ((u >> 16) & 1u)) >> 16;
    return (unsigned short)r;
}
__device__ inline float bf2f(unsigned short h) {
    return __uint_as_float(((unsigned int)h) << 16);
}

// fast tanh: (t-1)/(t+1), t = exp2(2x*log2e). ~7 VALU + 2 trans vs libm ~20.
__device__ inline float fast_tanh(float x) {
    float e = x * 2.8853900817779268f;            // 2*log2(e)
    e = fminf(fmaxf(e, -126.f), 126.f);
    float t = __builtin_amdgcn_exp2f(e);
    return (t - 1.0f) * __builtin_amdgcn_rcpf(t + 1.0f);
}

// ---------------- CSR build: dst counting sort + global-atomic out-degree ----
// R16: src-side sort removed — it only produced out-degrees. odeg[] is built
// with one global atomic per edge inside the dst histogram pass; nsrc is
// computed in k_fine. Deletes E scattered 4B writes (partial-line RMW), E
// reads, half the scan domain, and half of k_fine's blocks.
// Packing (dlocal<<17|src) requires N <= 2^17.

constexpr int CB = 256;

__global__ __launch_bounds__(256) void k_bucket_hist(const int* __restrict__ src,
                                                     const int* __restrict__ dst,
                                                     int* __restrict__ gH,
                                                     int* __restrict__ odeg,
                                                     int E, int K, int chunk) {
    extern __shared__ int lds[];
    for (int i = threadIdx.x; i < K; i += 256) lds[i] = 0;
    __syncthreads();
    int lo = blockIdx.x * chunk;
    int hi = lo + chunk; if (hi > E) hi = E;
    for (int i = lo + threadIdx.x; i < hi; i += 256) {
        atomicAdd(&lds[dst[i] >> 6], 1);
        atomicAdd(&odeg[src[i]], 1);
    }
    __syncthreads();
    for (int k = threadIdx.x; k < K; k += 256)
        gH[(size_t)k * CB + blockIdx.x] = lds[k];
}

__global__ __launch_bounds__(256) void k_bucket_scatter(const int* __restrict__ src,
                                                        const int* __restrict__ dst,
                                                        const int* __restrict__ gHS,
                                                        int* __restrict__ sortedAll,
                                                        int E, int K, int chunk) {
    extern __shared__ int lds[];
    int* bd = lds;
    for (int k = threadIdx.x; k < K; k += 256)
        bd[k] = gHS[(size_t)k * CB + blockIdx.x];
    __syncthreads();
    int lo = blockIdx.x * chunk;
    int hi = lo + chunk; if (hi > E) hi = E;
    for (int i = lo + threadIdx.x; i < hi; i += 256) {
        int d = dst[i], s = src[i];
        int pd = atomicAdd(&bd[d >> 6], 1);
        sortedAll[pd] = ((d & 63) << 17) | s;
    }
}

__global__ __launch_bounds__(256) void k_fine(const int* __restrict__ sortedAll,
                                              const int* __restrict__ gHS,
                                              const int* __restrict__ odeg,
                                              int* __restrict__ rowptr,
                                              int* __restrict__ colidx,
                                              float* __restrict__ nsrc,
                                              float* __restrict__ ndst,
                                              int E, int K, int N) {
    __shared__ int cnt[64], excl[64], rank[64];
    int k = blockIdx.x;
    int bstart = gHS[(size_t)k * CB];
    int bend   = gHS[(size_t)(k + 1) * CB];   // k==K-1 reads gHS[scanN] == E
    if (threadIdx.x < 64) { cnt[threadIdx.x] = 0; rank[threadIdx.x] = 0; }
    __syncthreads();
    for (int i = bstart + threadIdx.x; i < bend; i += 256)
        atomicAdd(&cnt[sortedAll[i] >> 17], 1);
    __syncthreads();
    if (threadIdx.x == 0) {
        int r = 0;
        for (int j = 0; j < 64; j++) { excl[j] = r; r += cnt[j]; }
    }
    __syncthreads();
    int node0 = k << 6;
    if (threadIdx.x < 64) {
        int node = node0 + threadIdx.x;
        if (node < N) {
            rowptr[node] = bstart + excl[threadIdx.x];
            int c = cnt[threadIdx.x];
            ndst[node] = c > 0 ? rsqrtf((float)c) : 0.f;
            int od = odeg[node];
            nsrc[node] = od > 0 ? rsqrtf((float)od) : 0.f;
        }
    }
    if (k == 0 && threadIdx.x == 0) rowptr[N] = E;
    for (int i = bstart + threadIdx.x; i < bend; i += 256) {
        int v = sortedAll[i];
        int nn = v >> 17;
        int r = atomicAdd(&rank[nn], 1);
        colidx[bstart + excl[nn] + r] = v & 0x1FFFF;
    }
}

// W (fp32, k-major [k][n]) -> Wt hi/lo, n-major [n][k], all 4 layers.
// Layer 0: bf16 pair. Layers 1-3: fp16 pair. Also zero-inits odeg[0..n).
__global__ void k_prepW_all(const float* __restrict__ W0, const float* __restrict__ W1,
                            const float* __restrict__ W2, const float* __restrict__ W3,
                            unsigned short* __restrict__ h0, unsigned short* __restrict__ l0,
                            unsigned short* __restrict__ h1, unsigned short* __restrict__ l1,
                            unsigned short* __restrict__ h2, unsigned short* __restrict__ l2,
                            unsigned short* __restrict__ h3, unsigned short* __restrict__ l3,
                            int* __restrict__ odeg, int nodes) {
    int i = blockIdx.x * 256 + threadIdx.x;
    if (i < nodes) odeg[i] = 0;
    const float* W; unsigned short* wh; unsigned short* wl; int N; int base; bool bf;
    if      (i < 16384) { W = W0; wh = h0; wl = l0; N = 128; base = i;         bf = true;  }
    else if (i < 32768) { W = W1; wh = h1; wl = l1; N = 128; base = i - 16384; bf = false; }
    else if (i < 49152) { W = W2; wh = h2; wl = l2; N = 128; base = i - 32768; bf = false; }
    else if (i < 57344) { W = W3; wh = h3; wl = l3; N = 64;  base = i - 49152; bf = false; }
    else return;
    int n = base >> 7, k = base & 127;
    float w = W[k * N + n];
    if (bf) {
        unsigned short hb = f2bf_rne(w);
        unsigned short lb = f2bf_rne(w - bf2f(hb));
        wh[base] = hb; wl[base] = lb;
    } else {
        union { _Float16 f; unsigned short u; } H, L;
        H.f = (_Float16)w;
        L.f = (_Float16)(w - (float)H.f);
        wh[base] = H.u; wl[base] = L.u;
    }
}

// ---------------- device-wide exclusive scan (tile = 2048) ----------------

constexpr int SCAN_TILE = 2048;

__global__ __launch_bounds__(256) void k_scan_partial(const int* __restrict__ deg,
                                                      int* __restrict__ tilesum, int n) {
    __shared__ int red[256];
    int base = blockIdx.x * SCAN_TILE;
    int s = 0;
    for (int i = threadIdx.x; i < SCAN_TILE; i += 256) {
        int idx = base + i;
        if (idx < n) s += deg[idx];
    }
    red[threadIdx.x] = s;
    __syncthreads();
    for (int off = 128; off > 0; off >>= 1) {
        if (threadIdx.x < off) red[threadIdx.x] += red[threadIdx.x + off];
        __syncthreads();
    }
    if (threadIdx.x == 0) tilesum[blockIdx.x] = red[0];
}

__global__ void k_scan_tiles(int* __restrict__ tilesum, int* __restrict__ outArr,
                             int numTiles, int n) {
    if (threadIdx.x == 0 && blockIdx.x == 0) {
        int acc = 0;
        for (int i = 0; i < numTiles; i++) { int v = tilesum[i]; tilesum[i] = acc; acc += v; }
        outArr[n] = acc;
    }
}

__global__ __launch_bounds__(256) void k_scan_final(const int* __restrict__ deg,
                                                    const int* __restrict__ tilesum,
                                                    int* __restrict__ outArr, int n) {
    __shared__ int red[256];
    int base = blockIdx.x * SCAN_TILE;
    int lo = base + threadIdx.x * 8;
    int v[8]; int s = 0;
#pragma unroll
    for (int j = 0; j < 8; j++) {
        int idx = lo + j;
        v[j] = (idx < n) ? deg[idx] : 0;
        s += v[j];
    }
    red[threadIdx.x] = s;
    __syncthreads();
    for (int off = 1; off < 256; off <<= 1) {
        int x = red[threadIdx.x];
        int add = (threadIdx.x >= off) ? red[threadIdx.x - off] : 0;
        __syncthreads();
        red[threadIdx.x] = x + add;
        __syncthreads();
    }
    int excl = tilesum[blockIdx.x] + (threadIdx.x ? red[threadIdx.x - 1] : 0);
#pragma unroll
    for (int j = 0; j < 8; j++) {
        int idx = lo + j;
        if (idx < n) outArr[idx] = excl;
        excl += v[j];
    }
}

// ---------------- GEMM: B in LDS, A direct from global, RT row-tiles/wave ----
// R16: RT=2 for the fp16 layers — each wave computes 2 row-tiles against the
// SAME staged B fragments (ds_read:MFMA 1:1 -> 1:2, B staging per row halved,
// half the blocks). Per-element k-accumulation order unchanged -> bit-identical
// h. A/x loads non-temporal (read-once streams; keep W + h gather lines in L2).
// Writes fp16 h + a ZERO row at h[nrows*DOUT] for masked aggregate slots.

template <int DOUT, int SRC, int RT>
__global__ __launch_bounds__(256) void k_gemm_hyb(
        const float* __restrict__ xf, const _Float16* __restrict__ xq,
        const unsigned short* __restrict__ wth, const unsigned short* __restrict__ wtl,
        const float* __restrict__ nsrc, _Float16* __restrict__ h, int nrows) {
    constexpr int NT = DOUT / 16;
    constexpr int LDK = 72;          // 64 k-half + 8 pad (16B-aligned rows)
    __shared__ unsigned short Bh[DOUT * LDK], Bl[DOUT * LDK];

    int tid = threadIdx.x;
    int lane = tid & 63;
    int wv = tid >> 6;
    int quad = lane >> 4, l16 = lane & 15;
    int r0 = blockIdx.x * (64 * RT) + wv * (16 * RT);
    int rowA[RT];
#pragma unroll
    for (int t = 0; t < RT; t++) {
        int r = r0 + t * 16 + l16;
        rowA[t] = r < nrows ? r : nrows - 1;   // clamped load row
    }

    // zero row for the aggregate's masked edge slots
    if (blockIdx.x == 0 && tid < DOUT / 8) {
        f32x4 z = {0.f, 0.f, 0.f, 0.f};
        *(f32x4*)((char*)h + ((size_t)nrows * DOUT + tid * 8) * 2) = z;
    }

    f32x4 acc[RT][NT];
#pragma unroll
    for (int t = 0; t < RT; t++)
#pragma unroll
        for (int nt = 0; nt < NT; nt++) acc[t][nt] = (f32x4){0.f, 0.f, 0.f, 0.f};

    for (int kh = 0; kh < 2; kh++) {
        if (kh) __syncthreads();
        // stage B half: DOUT n-rows x 64 k
        for (int i = tid; i < DOUT * 16; i += 256) {
            int n = i >> 4, kb = i & 15;
            int koff = kh * 64 + kb * 4;
            *(ushort4*)&Bh[n * LDK + kb * 4] = *(const ushort4*)&wth[n * 128 + koff];
            *(ushort4*)&Bl[n * LDK + kb * 4] = *(const ushort4*)&wtl[n * 128 + koff];
        }
        __syncthreads();

#pragma unroll
        for (int kq = 0; kq < 2; kq++) {
            int koA = kh * 64 + kq * 32 + quad * 8;   // global k offset for A
            int koB = kq * 32 + quad * 8;             // LDS offset within half
            if (SRC == 0) {
                bf16x8 ah[RT], al[RT];
#pragma unroll
                for (int t = 0; t < RT; t++) {
                    const float* xp = &xf[(size_t)rowA[t] * 128 + koA];
                    f32x4 x0 = __builtin_nontemporal_load((const f32x4*)xp);
                    f32x4 x1 = __builtin_nontemporal_load((const f32x4*)(xp + 4));
                    union { bf16x8 v; unsigned short u[8]; } H, L;
                    float xs[8] = {x0[0], x0[1], x0[2], x0[3], x1[0], x1[1], x1[2], x1[3]};
#pragma unroll
                    for (int j = 0; j < 8; j++) {
                        H.u[j] = f2bf_rne(xs[j]);
                        L.u[j] = f2bf_rne(xs[j] - bf2f(H.u[j]));
                    }
                    ah[t] = H.v; al[t] = L.v;
                }
#pragma unroll
                for (int nt = 0; nt < NT; nt++) {
                    int n = nt * 16 + l16;
                    bf16x8 bh = *(const bf16x8*)&Bh[n * LDK + koB];
                    bf16x8 bl = *(const bf16x8*)&Bl[n * LDK + koB];
#pragma unroll
                    for (int t = 0; t < RT; t++) {
                        acc[t][nt] = __builtin_amdgcn_mfma_f32_16x16x32_bf16(ah[t], bh, acc[t][nt], 0, 0, 0);
                        acc[t][nt] = __builtin_amdgcn_mfma_f32_16x16x32_bf16(ah[t], bl, acc[t][nt], 0, 0, 0);
                        acc[t][nt] = __builtin_amdgcn_mfma_f32_16x16x32_bf16(al[t], bh, acc[t][nt], 0, 0, 0);
                    }
                }
            } else {
                f16x8 aq[RT];
#pragma unroll
                for (int t = 0; t < RT; t++)
                    aq[t] = __builtin_nontemporal_load((const f16x8*)&xq[(size_t)rowA[t] * 128 + koA]);
#pragma unroll
                for (int nt = 0; nt < NT; nt++) {
                    int n = nt * 16 + l16;
                    f16x8 bh = *(const f16x8*)&Bh[n * LDK + koB];
                    f16x8 bl = *(const f16x8*)&Bl[n * LDK + koB];
#pragma unroll
                    for (int t = 0; t < RT; t++) {
                        acc[t][nt] = __builtin_amdgcn_mfma_f32_16x16x32_f16(aq[t], bh, acc[t][nt], 0, 0, 0);
                        acc[t][nt] = __builtin_amdgcn_mfma_f32_16x16x32_f16(aq[t], bl, acc[t][nt], 0, 0, 0);
                    }
                }
            }
        }
    }

#pragma unroll
    for (int t = 0; t < RT; t++)
#pragma unroll
        for (int r = 0; r < 4; r++) {
            int row = r0 + t * 16 + quad * 4 + r;
            if (row < nrows) {
                float nm = nsrc[row];
#pragma unroll
                for (int nt = 0; nt < NT; nt++)
                    h[(size_t)row * DOUT + nt * 16 + l16] = (_Float16)(acc[t][nt][r] * nm);
            }
        }
}

// ---------------- aggregation: 16-lane-group-per-node (R2 form + nt I/O) ------
// At the ~3.5 TB/s scattered-line ceiling (R0/R2/R3/R4 all converge there).
// R16: x/out writes are non-temporal — written-once streams must not evict
// h gather lines from L2. colidx reads stay non-temporal.

template <int D, int MODE>
__global__ __launch_bounds__(256) void k_aggregate(const _Float16* __restrict__ h,
                                                   const int* __restrict__ rowptr,
                                                   const int* __restrict__ colidx,
                                                   const float* __restrict__ ndst,
                                                   const float* __restrict__ bias,
                                                   float* __restrict__ out,
                                                   _Float16* __restrict__ oq,
                                                   int n) {
    constexpr int FB = D / 8;              // lanes per node row (16B fp16 each)
    constexpr int GN = 64 / FB;            // nodes per wave
    constexpr int EU = 4;                  // edges in flight per group
    int wid  = (blockIdx.x * 256 + threadIdx.x) >> 6;
    int lane = threadIdx.x & 63;
    int fb = lane & (FB - 1);
    int g  = lane / FB;
    int waveCount = gridDim.x * 4;

    for (int nbase = wid * GN; nbase < n; nbase += waveCount * GN) {
        int node = nbase + g;
        bool vn = node < n;
        int beg = vn ? rowptr[node] : 0;
        int end = vn ? rowptr[node + 1] : 0;
        int m = end - beg;

        int mmax = m;
#pragma unroll
        for (int off = FB; off < 64; off <<= 1) {
            int t = __shfl_xor(mmax, off);
            mmax = mmax > t ? mmax : t;
        }

        float acc[8];
#pragma unroll
        for (int k = 0; k < 8; k++) acc[k] = 0.f;

        int cv = 0;
        for (int j0 = 0; j0 < mmax; j0 += EU) {
            if ((j0 & (FB - 1)) == 0) {
                int idx = beg + j0 + fb;
                cv = __builtin_nontemporal_load(&colidx[idx < end ? idx : 0]);
            }
            int s[EU];
#pragma unroll
            for (int u = 0; u < EU; u++) {
                int j = j0 + u;
                int sv = __shfl(cv, g * FB + (j & (FB - 1)));
                s[u] = j < m ? sv : n;             // row n = zero row
            }
            f16x8 v[EU];
#pragma unroll
            for (int u = 0; u < EU; u++)
                v[u] = *(const f16x8*)&h[(size_t)s[u] * D + fb * 8];
#pragma unroll
            for (int u = 0; u < EU; u++) {
#pragma unroll
                for (int k = 0; k < 8; k++)
                    acc[k] += (float)v[u][k];
            }
        }

        if (vn) {
            float nd = ndst[node];
            float bv[8];
            *(float4*)&bv[0] = ((const float4*)bias)[fb * 2];
            *(float4*)&bv[4] = ((const float4*)bias)[fb * 2 + 1];
            float vv[8];
#pragma unroll
            for (int k = 0; k < 8; k++) vv[k] = acc[k] * nd + bv[k];
            if (MODE == 1) {
                f16x8 q;
#pragma unroll
                for (int k = 0; k < 8; k++)
                    q[k] = (_Float16)fast_tanh(vv[k]);
                __builtin_nontemporal_store(q, (f16x8*)&oq[(size_t)node * D + fb * 8]);
            } else {
                __builtin_nontemporal_store(*(f32x4*)&vv[0], (f32x4*)&out[(size_t)node * D + fb * 8]);
                __builtin_nontemporal_store(*(f32x4*)&vv[4], (f32x4*)&out[(size_t)node * D + fb * 8 + 4]);
            }
        }
    }
}

// ---------------- host ----------------

extern "C" void kernel_launch(void* const* d_in, const int* in_sizes, int n_in,
                              void* d_out, int out_size, void* d_ws, size_t ws_size,
                              hipStream_t stream) {
    const float* features = (const float*)d_in[0];
    const int* edges      = (const int*)d_in[1];
    const float* W0 = (const float*)d_in[2]; const float* b0 = (const float*)d_in[3];
    const float* W1 = (const float*)d_in[4]; const float* b1 = (const float*)d_in[5];
    const float* W2 = (const float*)d_in[6]; const float* b2 = (const float*)d_in[7];
    const float* W3 = (const float*)d_in[8]; const float* b3 = (const float*)d_in[9];
    float* out = (float*)d_out;

    const int N = in_sizes[0] / 128;
    const int E = in_sizes[1] / 2;
    const int* src = edges;
    const int* dst = edges + E;
    const int K = (N + 63) >> 6;
    const int chunk = (E + CB - 1) / CB;
    const int scanN = K * CB;
    const int numTiles = (scanN + SCAN_TILE - 1) / SCAN_TILE;
    const size_t dynLds = (size_t)K * sizeof(int);

    char* p = (char*)d_ws;
    _Float16* bufH         = (_Float16*)p;       p += (size_t)N * 128 * 4;  // fp32-sized slot; row N = zero row
    _Float16* xq           = (_Float16*)p;       p += (size_t)(N + 1) * 128 * 2;
    int*   rowptr = (int*)p;   p += (((size_t)(N + 1) * 4 + 15) / 16) * 16;
    int*   colidx = (int*)p;   p += (size_t)E * 4;
    float* nsrc   = (float*)p; p += (size_t)N * 4;
    float* ndst   = (float*)p; p += (size_t)N * 4;
    int*   odeg   = (int*)p;   p += (size_t)N * 4;
    int*   tilesum= (int*)p;   p += (((size_t)(numTiles + 1) * 4 + 15) / 16) * 16;
    unsigned short* wt0h = (unsigned short*)p; p += 16384 * 2;
    unsigned short* wt0l = (unsigned short*)p; p += 16384 * 2;
    unsigned short* wt1h = (unsigned short*)p; p += 16384 * 2;
    unsigned short* wt1l = (unsigned short*)p; p += 16384 * 2;
    unsigned short* wt2h = (unsigned short*)p; p += 16384 * 2;
    unsigned short* wt2l = (unsigned short*)p; p += 16384 * 2;
    unsigned short* wt3h = (unsigned short*)p; p += 8192 * 2;
    unsigned short* wt3l = (unsigned short*)p; p += 8192 * 2;

    // transient counting-sort buffers aliased into xq region (E + 2*scanN+1 ints << xq bytes)
    char* q = (char*)xq;
    int* sortedAll = (int*)q; q += (size_t)E * 4;
    int* gH        = (int*)q; q += (size_t)scanN * 4;
    int* gHS       = (int*)q; q += (size_t)(scanN + 1) * 4;

    int prepBlocks = (N + 255) / 256; if (prepBlocks < 224) prepBlocks = 224;
    k_prepW_all<<<prepBlocks, 256, 0, stream>>>(W0, W1, W2, W3, wt0h, wt0l, wt1h, wt1l,
                                                wt2h, wt2l, wt3h, wt3l, odeg, N);
    k_bucket_hist<<<CB, 256, dynLds, stream>>>(src, dst, gH, odeg, E, K, chunk);
    k_scan_partial<<<numTiles, 256, 0, stream>>>(gH, tilesum, scanN);
    k_scan_tiles<<<1, 64, 0, stream>>>(tilesum, gHS, numTiles, scanN);
    k_scan_final<<<numTiles, 256, 0, stream>>>(gH, tilesum, gHS, scanN);
    k_bucket_scatter<<<CB, 256, dynLds, stream>>>(src, dst, gHS, sortedAll, E, K, chunk);
    k_fine<<<K, 256, 0, stream>>>(sortedAll, gHS, odeg, rowptr, colidx, nsrc, ndst, E, K, N);

    int gblk1 = (N + 63) / 64;     // RT=1 (layer 0)
    int gblk2 = (N + 127) / 128;   // RT=2 (layers 1-3)
    int ablk128 = (N + 15) / 16;   // 4 waves/block x 4 nodes/wave
    int ablk64  = (N + 31) / 32;   // 4 waves/block x 8 nodes/wave
    k_gemm_hyb<128, 0, 1><<<gblk1, 256, 0, stream>>>(features, nullptr, wt0h, wt0l, nsrc, bufH, N);
    k_aggregate<128, 1><<<ablk128, 256, 0, stream>>>(bufH, rowptr, colidx, ndst, b0, nullptr, xq, N);
    k_gemm_hyb<128, 1, 2><<<gblk2, 256, 0, stream>>>(nullptr, xq, wt1h, wt1l, nsrc, bufH, N);
    k_aggregate<128, 1><<<ablk128, 256, 0, stream>>>(bufH, rowptr, colidx, ndst, b1, nullptr, xq, N);
    k_gemm_hyb<128, 1, 2><<<gblk2, 256, 0, stream>>>(nullptr, xq, wt2h, wt2l, nsrc, bufH, N);
    k_aggregate<128, 1><<<ablk128, 256, 0, stream>>>(bufH, rowptr, colidx, ndst, b2, nullptr, xq, N);
    k_gemm_hyb<64, 1, 2><<<gblk2, 256, 0, stream>>>(nullptr, xq, wt3h, wt3l, nsrc, bufH, N);
    k_aggregate<64, 0><<<ablk64, 256, 0, stream>>>(bufH, rowptr, colidx, ndst, b3, out, nullptr, N);
}

// Round 7
// 530.477 us; speedup vs baseline: 1.0051x; 1.0051x over previous
//
#include <hip/hip_runtime.h>
#include <cmath>

typedef __attribute__((ext_vector_type(8))) short bf16x8;
typedef __attribute__((ext_vector_type(8))) _Float16 f16x8;
typedef __attribute__((ext_vector_type(4))) float f32x4;

__device__ inline unsigned short f2bf_rne(float f) {
    unsigned int u = __float_as_uint(f);
    unsigned int r = (u + 0x7FFFu + ((u >> 16) & 1u)) >> 16;
    return (unsigned short)r;
}
__device__ inline float bf2f(unsigned short h) {
    return __uint_as_float(((unsigned int)h) << 16);
}

// fast tanh: (t-1)/(t+1), t = exp2(2x*log2e). ~7 VALU + 2 trans vs libm ~20.
__device__ inline float fast_tanh(float x) {
    float e = x * 2.8853900817779268f;            // 2*log2(e)
    e = fminf(fmaxf(e, -126.f), 126.f);
    float t = __builtin_amdgcn_exp2f(e);
    return (t - 1.0f) * __builtin_amdgcn_rcpf(t + 1.0f);
}

// ---------------- CSR build via two-level counting sort (R7/R8, restored R17) --
// R16's global-atomic odeg was a 74us disaster (cross-XCD line ping-pong,
// ~46ns/atomic). The dual counting sort is ~3x cheaper for the same info.
// Packing (dlocal<<17|src) requires N <= 2^17.

constexpr int CB = 256;

__global__ __launch_bounds__(256) void k_bucket_hist(const int* __restrict__ src,
                                                     const int* __restrict__ dst,
                                                     int* __restrict__ gH,
                                                     int E, int K, int scanN, int chunk) {
    extern __shared__ int lds[];
    int* hd = lds; int* hs = lds + K;
    for (int i = threadIdx.x; i < 2 * K; i += 256) lds[i] = 0;
    __syncthreads();
    int lo = blockIdx.x * chunk;
    int hi = lo + chunk; if (hi > E) hi = E;
    for (int i = lo + threadIdx.x; i < hi; i += 256) {
        atomicAdd(&hd[dst[i] >> 6], 1);
        atomicAdd(&hs[src[i] >> 6], 1);
    }
    __syncthreads();
    for (int k = threadIdx.x; k < K; k += 256) {
        gH[(size_t)k * CB + blockIdx.x] = hd[k];
        gH[(size_t)(scanN + k * CB) + blockIdx.x] = hs[k];
    }
}

__global__ __launch_bounds__(256) void k_bucket_scatter(const int* __restrict__ src,
                                                        const int* __restrict__ dst,
                                                        const int* __restrict__ gHS,
                                                        int* __restrict__ sortedAll,
                                                        int E, int K, int scanN, int chunk) {
    extern __shared__ int lds[];
    int* bd = lds; int* bs = lds + K;
    for (int k = threadIdx.x; k < K; k += 256) {
        bd[k] = gHS[(size_t)k * CB + blockIdx.x];
        bs[k] = gHS[(size_t)(scanN + k * CB) + blockIdx.x];
    }
    __syncthreads();
    int lo = blockIdx.x * chunk;
    int hi = lo + chunk; if (hi > E) hi = E;
    for (int i = lo + threadIdx.x; i < hi; i += 256) {
        int d = dst[i], s = src[i];
        int pd = atomicAdd(&bd[d >> 6], 1);
        sortedAll[pd] = ((d & 63) << 17) | s;
        int ps = atomicAdd(&bs[s >> 6], 1);
        sortedAll[ps] = s;
    }
}

__global__ __launch_bounds__(256) void k_fine(const int* __restrict__ sortedAll,
                                              const int* __restrict__ gHS,
                                              int* __restrict__ rowptr,
                                              int* __restrict__ colidx,
                                              float* __restrict__ nsrc,
                                              float* __restrict__ ndst,
                                              int E, int K, int scanN, int N) {
    __shared__ int cnt[64], excl[64], rank[64];
    int kb = blockIdx.x;
    bool isDst = kb < K;
    int k = isDst ? kb : kb - K;
    int bstart, bend;
    if (isDst) {
        bstart = gHS[(size_t)k * CB];
        bend = (k + 1 < K) ? gHS[(size_t)(k + 1) * CB] : E;
    } else {
        bstart = gHS[(size_t)(scanN + k * CB)];
        bend = (k + 1 < K) ? gHS[(size_t)(scanN + (k + 1) * CB)] : 2 * E;
    }
    if (threadIdx.x < 64) { cnt[threadIdx.x] = 0; rank[threadIdx.x] = 0; }
    __syncthreads();
    if (isDst) {
        for (int i = bstart + threadIdx.x; i < bend; i += 256)
            atomicAdd(&cnt[sortedAll[i] >> 17], 1);
    } else {
        for (int i = bstart + threadIdx.x; i < bend; i += 256)
            atomicAdd(&cnt[sortedAll[i] & 63], 1);
    }
    __syncthreads();
    if (isDst) {
        if (threadIdx.x == 0) {
            int r = 0;
            for (int j = 0; j < 64; j++) { excl[j] = r; r += cnt[j]; }
        }
        __syncthreads();
        int node0 = k << 6;
        if (threadIdx.x < 64) {
            int node = node0 + threadIdx.x;
            if (node < N) {
                rowptr[node] = bstart + excl[threadIdx.x];
                int c = cnt[threadIdx.x];
                ndst[node] = c > 0 ? rsqrtf((float)c) : 0.f;
            }
        }
        if (k == 0 && threadIdx.x == 0) rowptr[N] = E;
        for (int i = bstart + threadIdx.x; i < bend; i += 256) {
            int v = sortedAll[i];
            int n = v >> 17;
            int r = atomicAdd(&rank[n], 1);
            colidx[bstart + excl[n] + r] = v & 0x1FFFF;
        }
    } else {
        int node = (k << 6) + threadIdx.x;
        if (threadIdx.x < 64 && node < N) {
            int c = cnt[threadIdx.x];
            nsrc[node] = c > 0 ? rsqrtf((float)c) : 0.f;
        }
    }
}

// W (fp32, k-major [k][n]) -> Wt hi/lo, n-major [n][k], all 4 layers.
// Layer 0: bf16 pair. Layers 1-3: fp16 pair.
__global__ void k_prepW_all(const float* __restrict__ W0, const float* __restrict__ W1,
                            const float* __restrict__ W2, const float* __restrict__ W3,
                            unsigned short* __restrict__ h0, unsigned short* __restrict__ l0,
                            unsigned short* __restrict__ h1, unsigned short* __restrict__ l1,
                            unsigned short* __restrict__ h2, unsigned short* __restrict__ l2,
                            unsigned short* __restrict__ h3, unsigned short* __restrict__ l3) {
    int i = blockIdx.x * 256 + threadIdx.x;
    const float* W; unsigned short* wh; unsigned short* wl; int N; int base; bool bf;
    if      (i < 16384) { W = W0; wh = h0; wl = l0; N = 128; base = i;         bf = true;  }
    else if (i < 32768) { W = W1; wh = h1; wl = l1; N = 128; base = i - 16384; bf = false; }
    else if (i < 49152) { W = W2; wh = h2; wl = l2; N = 128; base = i - 32768; bf = false; }
    else if (i < 57344) { W = W3; wh = h3; wl = l3; N = 64;  base = i - 49152; bf = false; }
    else return;
    int n = base >> 7, k = base & 127;
    float w = W[k * N + n];
    if (bf) {
        unsigned short hb = f2bf_rne(w);
        unsigned short lb = f2bf_rne(w - bf2f(hb));
        wh[base] = hb; wl[base] = lb;
    } else {
        union { _Float16 f; unsigned short u; } H, L;
        H.f = (_Float16)w;
        L.f = (_Float16)(w - (float)H.f);
        wh[base] = H.u; wl[base] = L.u;
    }
}

// ---------------- device-wide exclusive scan (tile = 2048) ----------------

constexpr int SCAN_TILE = 2048;

__global__ __launch_bounds__(256) void k_scan_partial(const int* __restrict__ deg,
                                                      int* __restrict__ tilesum, int n) {
    __shared__ int red[256];
    int base = blockIdx.x * SCAN_TILE;
    int s = 0;
    for (int i = threadIdx.x; i < SCAN_TILE; i += 256) {
        int idx = base + i;
        if (idx < n) s += deg[idx];
    }
    red[threadIdx.x] = s;
    __syncthreads();
    for (int off = 128; off > 0; off >>= 1) {
        if (threadIdx.x < off) red[threadIdx.x] += red[threadIdx.x + off];
        __syncthreads();
    }
    if (threadIdx.x == 0) tilesum[blockIdx.x] = red[0];
}

__global__ void k_scan_tiles(int* __restrict__ tilesum, int* __restrict__ outArr,
                             int numTiles, int n) {
    if (threadIdx.x == 0 && blockIdx.x == 0) {
        int acc = 0;
        for (int i = 0; i < numTiles; i++) { int v = tilesum[i]; tilesum[i] = acc; acc += v; }
        outArr[n] = acc;
    }
}

__global__ __launch_bounds__(256) void k_scan_final(const int* __restrict__ deg,
                                                    const int* __restrict__ tilesum,
                                                    int* __restrict__ outArr, int n) {
    __shared__ int red[256];
    int base = blockIdx.x * SCAN_TILE;
    int lo = base + threadIdx.x * 8;
    int v[8]; int s = 0;
#pragma unroll
    for (int j = 0; j < 8; j++) {
        int idx = lo + j;
        v[j] = (idx < n) ? deg[idx] : 0;
        s += v[j];
    }
    red[threadIdx.x] = s;
    __syncthreads();
    for (int off = 1; off < 256; off <<= 1) {
        int x = red[threadIdx.x];
        int add = (threadIdx.x >= off) ? red[threadIdx.x - off] : 0;
        __syncthreads();
        red[threadIdx.x] = x + add;
        __syncthreads();
    }
    int excl = tilesum[blockIdx.x] + (threadIdx.x ? red[threadIdx.x - 1] : 0);
#pragma unroll
    for (int j = 0; j < 8; j++) {
        int idx = lo + j;
        if (idx < n) outArr[idx] = excl;
        excl += v[j];
    }
}

// ---------------- GEMM: B in LDS, A direct from global, RT row-tiles/wave ----
// RT=2 for the fp16 layers — each wave computes 2 row-tiles against the SAME
// staged B fragments (ds_read:MFMA 1:1 -> 1:2, half the blocks). Per-element
// k-accumulation order unchanged -> bit-identical h. A/x loads non-temporal.
// Writes fp16 h + a ZERO row at h[nrows*DOUT] for masked aggregate slots.

template <int DOUT, int SRC, int RT>
__global__ __launch_bounds__(256) void k_gemm_hyb(
        const float* __restrict__ xf, const _Float16* __restrict__ xq,
        const unsigned short* __restrict__ wth, const unsigned short* __restrict__ wtl,
        const float* __restrict__ nsrc, _Float16* __restrict__ h, int nrows) {
    constexpr int NT = DOUT / 16;
    constexpr int LDK = 72;          // 64 k-half + 8 pad (16B-aligned rows)
    __shared__ unsigned short Bh[DOUT * LDK], Bl[DOUT * LDK];

    int tid = threadIdx.x;
    int lane = tid & 63;
    int wv = tid >> 6;
    int quad = lane >> 4, l16 = lane & 15;
    int r0 = blockIdx.x * (64 * RT) + wv * (16 * RT);
    int rowA[RT];
#pragma unroll
    for (int t = 0; t < RT; t++) {
        int r = r0 + t * 16 + l16;
        rowA[t] = r < nrows ? r : nrows - 1;   // clamped load row
    }

    // zero row for the aggregate's masked edge slots
    if (blockIdx.x == 0 && tid < DOUT / 8) {
        f32x4 z = {0.f, 0.f, 0.f, 0.f};
        *(f32x4*)((char*)h + ((size_t)nrows * DOUT + tid * 8) * 2) = z;
    }

    f32x4 acc[RT][NT];
#pragma unroll
    for (int t = 0; t < RT; t++)
#pragma unroll
        for (int nt = 0; nt < NT; nt++) acc[t][nt] = (f32x4){0.f, 0.f, 0.f, 0.f};

    for (int kh = 0; kh < 2; kh++) {
        if (kh) __syncthreads();
        // stage B half: DOUT n-rows x 64 k
        for (int i = tid; i < DOUT * 16; i += 256) {
            int n = i >> 4, kb = i & 15;
            int koff = kh * 64 + kb * 4;
            *(ushort4*)&Bh[n * LDK + kb * 4] = *(const ushort4*)&wth[n * 128 + koff];
            *(ushort4*)&Bl[n * LDK + kb * 4] = *(const ushort4*)&wtl[n * 128 + koff];
        }
        __syncthreads();

#pragma unroll
        for (int kq = 0; kq < 2; kq++) {
            int koA = kh * 64 + kq * 32 + quad * 8;   // global k offset for A
            int koB = kq * 32 + quad * 8;             // LDS offset within half
            if (SRC == 0) {
                bf16x8 ah[RT], al[RT];
#pragma unroll
                for (int t = 0; t < RT; t++) {
                    const float* xp = &xf[(size_t)rowA[t] * 128 + koA];
                    f32x4 x0 = __builtin_nontemporal_load((const f32x4*)xp);
                    f32x4 x1 = __builtin_nontemporal_load((const f32x4*)(xp + 4));
                    union { bf16x8 v; unsigned short u[8]; } H, L;
                    float xs[8] = {x0[0], x0[1], x0[2], x0[3], x1[0], x1[1], x1[2], x1[3]};
#pragma unroll
                    for (int j = 0; j < 8; j++) {
                        H.u[j] = f2bf_rne(xs[j]);
                        L.u[j] = f2bf_rne(xs[j] - bf2f(H.u[j]));
                    }
                    ah[t] = H.v; al[t] = L.v;
                }
#pragma unroll
                for (int nt = 0; nt < NT; nt++) {
                    int n = nt * 16 + l16;
                    bf16x8 bh = *(const bf16x8*)&Bh[n * LDK + koB];
                    bf16x8 bl = *(const bf16x8*)&Bl[n * LDK + koB];
#pragma unroll
                    for (int t = 0; t < RT; t++) {
                        acc[t][nt] = __builtin_amdgcn_mfma_f32_16x16x32_bf16(ah[t], bh, acc[t][nt], 0, 0, 0);
                        acc[t][nt] = __builtin_amdgcn_mfma_f32_16x16x32_bf16(ah[t], bl, acc[t][nt], 0, 0, 0);
                        acc[t][nt] = __builtin_amdgcn_mfma_f32_16x16x32_bf16(al[t], bh, acc[t][nt], 0, 0, 0);
                    }
                }
            } else {
                f16x8 aq[RT];
#pragma unroll
                for (int t = 0; t < RT; t++)
                    aq[t] = __builtin_nontemporal_load((const f16x8*)&xq[(size_t)rowA[t] * 128 + koA]);
#pragma unroll
                for (int nt = 0; nt < NT; nt++) {
                    int n = nt * 16 + l16;
                    f16x8 bh = *(const f16x8*)&Bh[n * LDK + koB];
                    f16x8 bl = *(const f16x8*)&Bl[n * LDK + koB];
#pragma unroll
                    for (int t = 0; t < RT; t++) {
                        acc[t][nt] = __builtin_amdgcn_mfma_f32_16x16x32_f16(aq[t], bh, acc[t][nt], 0, 0, 0);
                        acc[t][nt] = __builtin_amdgcn_mfma_f32_16x16x32_f16(aq[t], bl, acc[t][nt], 0, 0, 0);
                    }
                }
            }
        }
    }

#pragma unroll
    for (int t = 0; t < RT; t++)
#pragma unroll
        for (int r = 0; r < 4; r++) {
            int row = r0 + t * 16 + quad * 4 + r;
            if (row < nrows) {
                float nm = nsrc[row];
#pragma unroll
                for (int nt = 0; nt < NT; nt++)
                    h[(size_t)row * DOUT + nt * 16 + l16] = (_Float16)(acc[t][nt][r] * nm);
            }
        }
}

// ---------------- aggregation: 16-lane-group-per-node (R2 form + nt I/O) ------
// At the ~3.5 TB/s scattered-line ceiling (R0/R2/R3/R4 all converge there).
// x/out writes non-temporal; colidx reads non-temporal.

template <int D, int MODE>
__global__ __launch_bounds__(256) void k_aggregate(const _Float16* __restrict__ h,
                                                   const int* __restrict__ rowptr,
                                                   const int* __restrict__ colidx,
                                                   const float* __restrict__ ndst,
                                                   const float* __restrict__ bias,
                                                   float* __restrict__ out,
                                                   _Float16* __restrict__ oq,
                                                   int n) {
    constexpr int FB = D / 8;              // lanes per node row (16B fp16 each)
    constexpr int GN = 64 / FB;            // nodes per wave
    constexpr int EU = 4;                  // edges in flight per group
    int wid  = (blockIdx.x * 256 + threadIdx.x) >> 6;
    int lane = threadIdx.x & 63;
    int fb = lane & (FB - 1);
    int g  = lane / FB;
    int waveCount = gridDim.x * 4;

    for (int nbase = wid * GN; nbase < n; nbase += waveCount * GN) {
        int node = nbase + g;
        bool vn = node < n;
        int beg = vn ? rowptr[node] : 0;
        int end = vn ? rowptr[node + 1] : 0;
        int m = end - beg;

        int mmax = m;
#pragma unroll
        for (int off = FB; off < 64; off <<= 1) {
            int t = __shfl_xor(mmax, off);
            mmax = mmax > t ? mmax : t;
        }

        float acc[8];
#pragma unroll
        for (int k = 0; k < 8; k++) acc[k] = 0.f;

        int cv = 0;
        for (int j0 = 0; j0 < mmax; j0 += EU) {
            if ((j0 & (FB - 1)) == 0) {
                int idx = beg + j0 + fb;
                cv = __builtin_nontemporal_load(&colidx[idx < end ? idx : 0]);
            }
            int s[EU];
#pragma unroll
            for (int u = 0; u < EU; u++) {
                int j = j0 + u;
                int sv = __shfl(cv, g * FB + (j & (FB - 1)));
                s[u] = j < m ? sv : n;             // row n = zero row
            }
            f16x8 v[EU];
#pragma unroll
            for (int u = 0; u < EU; u++)
                v[u] = *(const f16x8*)&h[(size_t)s[u] * D + fb * 8];
#pragma unroll
            for (int u = 0; u < EU; u++) {
#pragma unroll
                for (int k = 0; k < 8; k++)
                    acc[k] += (float)v[u][k];
            }
        }

        if (vn) {
            float nd = ndst[node];
            float bv[8];
            *(float4*)&bv[0] = ((const float4*)bias)[fb * 2];
            *(float4*)&bv[4] = ((const float4*)bias)[fb * 2 + 1];
            float vv[8];
#pragma unroll
            for (int k = 0; k < 8; k++) vv[k] = acc[k] * nd + bv[k];
            if (MODE == 1) {
                f16x8 q;
#pragma unroll
                for (int k = 0; k < 8; k++)
                    q[k] = (_Float16)fast_tanh(vv[k]);
                __builtin_nontemporal_store(q, (f16x8*)&oq[(size_t)node * D + fb * 8]);
            } else {
                __builtin_nontemporal_store(*(f32x4*)&vv[0], (f32x4*)&out[(size_t)node * D + fb * 8]);
                __builtin_nontemporal_store(*(f32x4*)&vv[4], (f32x4*)&out[(size_t)node * D + fb * 8 + 4]);
            }
        }
    }
}

// ---------------- host ----------------

extern "C" void kernel_launch(void* const* d_in, const int* in_sizes, int n_in,
                              void* d_out, int out_size, void* d_ws, size_t ws_size,
                              hipStream_t stream) {
    const float* features = (const float*)d_in[0];
    const int* edges      = (const int*)d_in[1];
    const float* W0 = (const float*)d_in[2]; const float* b0 = (const float*)d_in[3];
    const float* W1 = (const float*)d_in[4]; const float* b1 = (const float*)d_in[5];
    const float* W2 = (const float*)d_in[6]; const float* b2 = (const float*)d_in[7];
    const float* W3 = (const float*)d_in[8]; const float* b3 = (const float*)d_in[9];
    float* out = (float*)d_out;

    const int N = in_sizes[0] / 128;
    const int E = in_sizes[1] / 2;
    const int* src = edges;
    const int* dst = edges + E;
    const int K = (N + 63) >> 6;
    const int chunk = (E + CB - 1) / CB;
    const int scanN = K * CB;
    const int n2 = 2 * scanN;
    const int numTiles = (n2 + SCAN_TILE - 1) / SCAN_TILE;
    const size_t dynLds = (size_t)2 * K * sizeof(int);

    char* p = (char*)d_ws;
    _Float16* bufH         = (_Float16*)p;       p += (size_t)N * 128 * 4;  // fp32-sized slot; row N = zero row
    _Float16* xq           = (_Float16*)p;       p += (size_t)(N + 1) * 128 * 2;
    char*     xspare       = p;                  p += (size_t)(N + 1) * 128 * 2;  // transient-sort spill
    int*   rowptr = (int*)p;   p += (((size_t)(N + 1) * 4 + 15) / 16) * 16;
    int*   colidx = (int*)p;   p += (size_t)E * 4;
    float* nsrc   = (float*)p; p += (size_t)N * 4;
    float* ndst   = (float*)p; p += (size_t)N * 4;
    int*   tilesum= (int*)p;   p += (((size_t)(numTiles + 1) * 4 + 15) / 16) * 16;
    unsigned short* wt0h = (unsigned short*)p; p += 16384 * 2;
    unsigned short* wt0l = (unsigned short*)p; p += 16384 * 2;
    unsigned short* wt1h = (unsigned short*)p; p += 16384 * 2;
    unsigned short* wt1l = (unsigned short*)p; p += 16384 * 2;
    unsigned short* wt2h = (unsigned short*)p; p += 16384 * 2;
    unsigned short* wt2l = (unsigned short*)p; p += 16384 * 2;
    unsigned short* wt3h = (unsigned short*)p; p += 8192 * 2;
    unsigned short* wt3l = (unsigned short*)p; p += 8192 * 2;

    // transient counting-sort buffers aliased into xq/xspare region
    char* q = (char*)xq;
    int* sortedAll = (int*)q; q += (size_t)2 * E * 4;
    int* gH        = (int*)q; q += (size_t)n2 * 4;
    int* gHS       = (int*)q; q += (size_t)(n2 + 1) * 4;
    (void)xspare;

    k_prepW_all<<<224, 256, 0, stream>>>(W0, W1, W2, W3, wt0h, wt0l, wt1h, wt1l,
                                         wt2h, wt2l, wt3h, wt3l);
    k_bucket_hist<<<CB, 256, dynLds, stream>>>(src, dst, gH, E, K, scanN, chunk);
    k_scan_partial<<<numTiles, 256, 0, stream>>>(gH, tilesum, n2);
    k_scan_tiles<<<1, 64, 0, stream>>>(tilesum, gHS, numTiles, n2);
    k_scan_final<<<numTiles, 256, 0, stream>>>(gH, tilesum, gHS, n2);
    k_bucket_scatter<<<CB, 256, dynLds, stream>>>(src, dst, gHS, sortedAll, E, K, scanN, chunk);
    k_fine<<<2 * K, 256, 0, stream>>>(sortedAll, gHS, rowptr, colidx, nsrc, ndst, E, K, scanN, N);

    int gblk1 = (N + 63) / 64;     // RT=1 (layer 0)
    int gblk2 = (N + 127) / 128;   // RT=2 (layers 1-3)
    int ablk128 = (N + 15) / 16;   // 4 waves/block x 4 nodes/wave
    int ablk64  = (N + 31) / 32;   // 4 waves/block x 8 nodes/wave
    k_gemm_hyb<128, 0, 1><<<gblk1, 256, 0, stream>>>(features, nullptr, wt0h, wt0l, nsrc, bufH, N);
    k_aggregate<128, 1><<<ablk128, 256, 0, stream>>>(bufH, rowptr, colidx, ndst, b0, nullptr, xq, N);
    k_gemm_hyb<128, 1, 2><<<gblk2, 256, 0, stream>>>(nullptr, xq, wt1h, wt1l, nsrc, bufH, N);
    k_aggregate<128, 1><<<ablk128, 256, 0, stream>>>(bufH, rowptr, colidx, ndst, b1, nullptr, xq, N);
    k_gemm_hyb<128, 1, 2><<<gblk2, 256, 0, stream>>>(nullptr, xq, wt2h, wt2l, nsrc, bufH, N);
    k_aggregate<128, 1><<<ablk128, 256, 0, stream>>>(bufH, rowptr, colidx, ndst, b2, nullptr, xq, N);
    k_gemm_hyb<64, 1, 2><<<gblk2, 256, 0, stream>>>(nullptr, xq, wt3h, wt3l, nsrc, bufH, N);
    k_aggregate<64, 0><<<ablk64, 256, 0, stream>>>(bufH, rowptr, colidx, ndst, b3, out, nullptr, N);
}

// Round 8
// 513.966 us; speedup vs baseline: 1.0374x; 1.0321x over previous
//
#include <hip/hip_runtime.h>
#include <cmath>

typedef __attribute__((ext_vector_type(8))) short bf16x8;
typedef __attribute__((ext_vector_type(8))) _Float16 f16x8;
typedef __attribute__((ext_vector_type(4))) float f32x4;

__device__ inline unsigned short f2bf_rne(float f) {
    unsigned int u = __float_as_uint(f);
    unsigned int r = (u + 0x7FFFu + ((u >> 16) & 1u)) >> 16;
    return (unsigned short)r;
}
__device__ inline float bf2f(unsigned short h) {
    return __uint_as_float(((unsigned int)h) << 16);
}

// fast tanh: (t-1)/(t+1), t = exp2(2x*log2e). ~7 VALU + 2 trans vs libm ~20.
__device__ inline float fast_tanh(float x) {
    float e = x * 2.8853900817779268f;            // 2*log2(e)
    e = fminf(fmaxf(e, -126.f), 126.f);
    float t = __builtin_amdgcn_exp2f(e);
    return (t - 1.0f) * __builtin_amdgcn_rcpf(t + 1.0f);
}

// ---------------- CSR build via two-level counting sort (R7/R8) ----------------
// R18: exact revert to the R4 anchor (508.9us). R6's global-atomic odeg (74us,
// cross-XCD line ping-pong) and R6/R7's RT=2 + nt-store GEMM bundle (+21us,
// suspected VGPR-cliff occupancy drop) are both rejected by bisection.
// Packing (dlocal<<17|src) requires N <= 2^17.

constexpr int CB = 256;

__global__ __launch_bounds__(256) void k_bucket_hist(const int* __restrict__ src,
                                                     const int* __restrict__ dst,
                                                     int* __restrict__ gH,
                                                     int E, int K, int scanN, int chunk) {
    extern __shared__ int lds[];
    int* hd = lds; int* hs = lds + K;
    for (int i = threadIdx.x; i < 2 * K; i += 256) lds[i] = 0;
    __syncthreads();
    int lo = blockIdx.x * chunk;
    int hi = lo + chunk; if (hi > E) hi = E;
    for (int i = lo + threadIdx.x; i < hi; i += 256) {
        atomicAdd(&hd[dst[i] >> 6], 1);
        atomicAdd(&hs[src[i] >> 6], 1);
    }
    __syncthreads();
    for (int k = threadIdx.x; k < K; k += 256) {
        gH[(size_t)k * CB + blockIdx.x] = hd[k];
        gH[(size_t)(scanN + k * CB) + blockIdx.x] = hs[k];
    }
}

__global__ __launch_bounds__(256) void k_bucket_scatter(const int* __restrict__ src,
                                                        const int* __restrict__ dst,
                                                        const int* __restrict__ gHS,
                                                        int* __restrict__ sortedAll,
                                                        int E, int K, int scanN, int chunk) {
    extern __shared__ int lds[];
    int* bd = lds; int* bs = lds + K;
    for (int k = threadIdx.x; k < K; k += 256) {
        bd[k] = gHS[(size_t)k * CB + blockIdx.x];
        bs[k] = gHS[(size_t)(scanN + k * CB) + blockIdx.x];
    }
    __syncthreads();
    int lo = blockIdx.x * chunk;
    int hi = lo + chunk; if (hi > E) hi = E;
    for (int i = lo + threadIdx.x; i < hi; i += 256) {
        int d = dst[i], s = src[i];
        int pd = atomicAdd(&bd[d >> 6], 1);
        sortedAll[pd] = ((d & 63) << 17) | s;
        int ps = atomicAdd(&bs[s >> 6], 1);
        sortedAll[ps] = s;
    }
}

__global__ __launch_bounds__(256) void k_fine(const int* __restrict__ sortedAll,
                                              const int* __restrict__ gHS,
                                              int* __restrict__ rowptr,
                                              int* __restrict__ colidx,
                                              float* __restrict__ nsrc,
                                              float* __restrict__ ndst,
                                              int E, int K, int scanN, int N) {
    __shared__ int cnt[64], excl[64], rank[64];
    int kb = blockIdx.x;
    bool isDst = kb < K;
    int k = isDst ? kb : kb - K;
    int bstart, bend;
    if (isDst) {
        bstart = gHS[(size_t)k * CB];
        bend = (k + 1 < K) ? gHS[(size_t)(k + 1) * CB] : E;
    } else {
        bstart = gHS[(size_t)(scanN + k * CB)];
        bend = (k + 1 < K) ? gHS[(size_t)(scanN + (k + 1) * CB)] : 2 * E;
    }
    if (threadIdx.x < 64) { cnt[threadIdx.x] = 0; rank[threadIdx.x] = 0; }
    __syncthreads();
    if (isDst) {
        for (int i = bstart + threadIdx.x; i < bend; i += 256)
            atomicAdd(&cnt[sortedAll[i] >> 17], 1);
    } else {
        for (int i = bstart + threadIdx.x; i < bend; i += 256)
            atomicAdd(&cnt[sortedAll[i] & 63], 1);
    }
    __syncthreads();
    if (isDst) {
        if (threadIdx.x == 0) {
            int r = 0;
            for (int j = 0; j < 64; j++) { excl[j] = r; r += cnt[j]; }
        }
        __syncthreads();
        int node0 = k << 6;
        if (threadIdx.x < 64) {
            int node = node0 + threadIdx.x;
            if (node < N) {
                rowptr[node] = bstart + excl[threadIdx.x];
                int c = cnt[threadIdx.x];
                ndst[node] = c > 0 ? rsqrtf((float)c) : 0.f;
            }
        }
        if (k == 0 && threadIdx.x == 0) rowptr[N] = E;
        for (int i = bstart + threadIdx.x; i < bend; i += 256) {
            int v = sortedAll[i];
            int n = v >> 17;
            int r = atomicAdd(&rank[n], 1);
            colidx[bstart + excl[n] + r] = v & 0x1FFFF;
        }
    } else {
        int node = (k << 6) + threadIdx.x;
        if (threadIdx.x < 64 && node < N) {
            int c = cnt[threadIdx.x];
            nsrc[node] = c > 0 ? rsqrtf((float)c) : 0.f;
        }
    }
}

// W (fp32, k-major [k][n]) -> Wt hi/lo, n-major [n][k], all 4 layers.
// Layer 0: bf16 pair (GEMM0 consumes fp32 features via bf16 path).
// Layers 1-3: fp16 pair (GEMM consumes fp16 x via f16 MFMA, 2 MFMAs/step).
__global__ void k_prepW_all(const float* __restrict__ W0, const float* __restrict__ W1,
                            const float* __restrict__ W2, const float* __restrict__ W3,
                            unsigned short* __restrict__ h0, unsigned short* __restrict__ l0,
                            unsigned short* __restrict__ h1, unsigned short* __restrict__ l1,
                            unsigned short* __restrict__ h2, unsigned short* __restrict__ l2,
                            unsigned short* __restrict__ h3, unsigned short* __restrict__ l3) {
    int i = blockIdx.x * 256 + threadIdx.x;
    const float* W; unsigned short* wh; unsigned short* wl; int N; int base; bool bf;
    if      (i < 16384) { W = W0; wh = h0; wl = l0; N = 128; base = i;         bf = true;  }
    else if (i < 32768) { W = W1; wh = h1; wl = l1; N = 128; base = i - 16384; bf = false; }
    else if (i < 49152) { W = W2; wh = h2; wl = l2; N = 128; base = i - 32768; bf = false; }
    else if (i < 57344) { W = W3; wh = h3; wl = l3; N = 64;  base = i - 49152; bf = false; }
    else return;
    int n = base >> 7, k = base & 127;
    float w = W[k * N + n];
    if (bf) {
        unsigned short hb = f2bf_rne(w);
        unsigned short lb = f2bf_rne(w - bf2f(hb));
        wh[base] = hb; wl[base] = lb;
    } else {
        union { _Float16 f; unsigned short u; } H, L;
        H.f = (_Float16)w;
        L.f = (_Float16)(w - (float)H.f);
        wh[base] = H.u; wl[base] = L.u;
    }
}

// ---------------- device-wide exclusive scan (tile = 2048) ----------------

constexpr int SCAN_TILE = 2048;

__global__ __launch_bounds__(256) void k_scan_partial(const int* __restrict__ deg,
                                                      int* __restrict__ tilesum, int n) {
    __shared__ int red[256];
    int base = blockIdx.x * SCAN_TILE;
    int s = 0;
    for (int i = threadIdx.x; i < SCAN_TILE; i += 256) {
        int idx = base + i;
        if (idx < n) s += deg[idx];
    }
    red[threadIdx.x] = s;
    __syncthreads();
    for (int off = 128; off > 0; off >>= 1) {
        if (threadIdx.x < off) red[threadIdx.x] += red[threadIdx.x + off];
        __syncthreads();
    }
    if (threadIdx.x == 0) tilesum[blockIdx.x] = red[0];
}

__global__ void k_scan_tiles(int* __restrict__ tilesum, int* __restrict__ outArr,
                             int numTiles, int n) {
    if (threadIdx.x == 0 && blockIdx.x == 0) {
        int acc = 0;
        for (int i = 0; i < numTiles; i++) { int v = tilesum[i]; tilesum[i] = acc; acc += v; }
        outArr[n] = acc;
    }
}

__global__ __launch_bounds__(256) void k_scan_final(const int* __restrict__ deg,
                                                    const int* __restrict__ tilesum,
                                                    int* __restrict__ outArr, int n) {
    __shared__ int red[256];
    int base = blockIdx.x * SCAN_TILE;
    int lo = base + threadIdx.x * 8;
    int v[8]; int s = 0;
#pragma unroll
    for (int j = 0; j < 8; j++) {
        int idx = lo + j;
        v[j] = (idx < n) ? deg[idx] : 0;
        s += v[j];
    }
    red[threadIdx.x] = s;
    __syncthreads();
    for (int off = 1; off < 256; off <<= 1) {
        int x = red[threadIdx.x];
        int add = (threadIdx.x >= off) ? red[threadIdx.x - off] : 0;
        __syncthreads();
        red[threadIdx.x] = x + add;
        __syncthreads();
    }
    int excl = tilesum[blockIdx.x] + (threadIdx.x ? red[threadIdx.x - 1] : 0);
#pragma unroll
    for (int j = 0; j < 8; j++) {
        int idx = lo + j;
        if (idx < n) outArr[idx] = excl;
        excl += v[j];
    }
}

// ---------------- GEMM: B in LDS, A direct from global (R11/R15 form) ----------
// SRC==0: A = fp32 features -> bf16 hi/lo split, B = bf16 hi/lo, 3 bf16 MFMAs.
// SRC==1: A = fp16 x (single), B = fp16 hi/lo, 2 f16 MFMAs.
// RT=1 only: R6/R7's RT=2 regressed (~+5us/GEMM, suspected VGPR-cliff).
// Writes fp16 h + a ZERO row at h[nrows*DOUT] for masked aggregate slots.

template <int DOUT, int SRC>
__global__ __launch_bounds__(256) void k_gemm_hyb(
        const float* __restrict__ xf, const _Float16* __restrict__ xq,
        const unsigned short* __restrict__ wth, const unsigned short* __restrict__ wtl,
        const float* __restrict__ nsrc, _Float16* __restrict__ h, int nrows) {
    constexpr int NT = DOUT / 16;    // n-tiles per wave (8 or 4), wave owns 16 rows x DOUT
    constexpr int LDK = 72;          // 64 k-half + 8 pad (16B-aligned rows)
    __shared__ unsigned short Bh[DOUT * LDK], Bl[DOUT * LDK];

    int tid = threadIdx.x;
    int lane = tid & 63;
    int wv = tid >> 6;
    int quad = lane >> 4, l16 = lane & 15;
    int r0 = blockIdx.x * 64 + wv * 16;
    int rowA = r0 + l16; if (rowA >= nrows) rowA = nrows - 1;   // clamped load row

    // zero row for the aggregate's masked edge slots
    if (blockIdx.x == 0 && tid < DOUT / 8) {
        f32x4 z = {0.f, 0.f, 0.f, 0.f};
        *(f32x4*)((char*)h + ((size_t)nrows * DOUT + tid * 8) * 2) = z;
    }

    f32x4 acc[NT];
#pragma unroll
    for (int nt = 0; nt < NT; nt++) acc[nt] = (f32x4){0.f, 0.f, 0.f, 0.f};

    for (int kh = 0; kh < 2; kh++) {
        if (kh) __syncthreads();
        // stage B half: DOUT n-rows x 64 k
        for (int i = tid; i < DOUT * 16; i += 256) {
            int n = i >> 4, kb = i & 15;
            int koff = kh * 64 + kb * 4;
            *(ushort4*)&Bh[n * LDK + kb * 4] = *(const ushort4*)&wth[n * 128 + koff];
            *(ushort4*)&Bl[n * LDK + kb * 4] = *(const ushort4*)&wtl[n * 128 + koff];
        }
        __syncthreads();

#pragma unroll
        for (int kq = 0; kq < 2; kq++) {
            int koA = kh * 64 + kq * 32 + quad * 8;   // global k offset for A
            int koB = kq * 32 + quad * 8;             // LDS offset within half
            if (SRC == 0) {
                const float* xp = &xf[(size_t)rowA * 128 + koA];
                f32x4 x0 = *(const f32x4*)xp;
                f32x4 x1 = *(const f32x4*)(xp + 4);
                union { bf16x8 v; unsigned short u[8]; } H, L;
                float xs[8] = {x0[0], x0[1], x0[2], x0[3], x1[0], x1[1], x1[2], x1[3]};
#pragma unroll
                for (int j = 0; j < 8; j++) {
                    H.u[j] = f2bf_rne(xs[j]);
                    L.u[j] = f2bf_rne(xs[j] - bf2f(H.u[j]));
                }
                bf16x8 ah = H.v, al = L.v;
#pragma unroll
                for (int nt = 0; nt < NT; nt++) {
                    int n = nt * 16 + l16;
                    bf16x8 bh = *(const bf16x8*)&Bh[n * LDK + koB];
                    bf16x8 bl = *(const bf16x8*)&Bl[n * LDK + koB];
                    acc[nt] = __builtin_amdgcn_mfma_f32_16x16x32_bf16(ah, bh, acc[nt], 0, 0, 0);
                    acc[nt] = __builtin_amdgcn_mfma_f32_16x16x32_bf16(ah, bl, acc[nt], 0, 0, 0);
                    acc[nt] = __builtin_amdgcn_mfma_f32_16x16x32_bf16(al, bh, acc[nt], 0, 0, 0);
                }
            } else {
                f16x8 aq = *(const f16x8*)&xq[(size_t)rowA * 128 + koA];
#pragma unroll
                for (int nt = 0; nt < NT; nt++) {
                    int n = nt * 16 + l16;
                    f16x8 bh = *(const f16x8*)&Bh[n * LDK + koB];
                    f16x8 bl = *(const f16x8*)&Bl[n * LDK + koB];
                    acc[nt] = __builtin_amdgcn_mfma_f32_16x16x32_f16(aq, bh, acc[nt], 0, 0, 0);
                    acc[nt] = __builtin_amdgcn_mfma_f32_16x16x32_f16(aq, bl, acc[nt], 0, 0, 0);
                }
            }
        }
    }

#pragma unroll
    for (int r = 0; r < 4; r++) {
        int row = r0 + quad * 4 + r;
        if (row < nrows) {
            float nm = nsrc[row];
#pragma unroll
            for (int nt = 0; nt < NT; nt++)
                h[(size_t)row * DOUT + nt * 16 + l16] = (_Float16)(acc[nt][r] * nm);
        }
    }
}

// ---------------- aggregation: 16-lane-group-per-node (R2 form, anchor) -------
// At the ~3.5 TB/s scattered-line ceiling (R0/R2/R3/R4 all converge there).
// colidx reads non-temporal (read-once stream); x/out writes REGULAR (R7
// showed nt stores here cost the consumer GEMM more than they save).

template <int D, int MODE>
__global__ __launch_bounds__(256) void k_aggregate(const _Float16* __restrict__ h,
                                                   const int* __restrict__ rowptr,
                                                   const int* __restrict__ colidx,
                                                   const float* __restrict__ ndst,
                                                   const float* __restrict__ bias,
                                                   float* __restrict__ out,
                                                   _Float16* __restrict__ oq,
                                                   int n) {
    constexpr int FB = D / 8;              // lanes per node row (16B fp16 each)
    constexpr int GN = 64 / FB;            // nodes per wave
    constexpr int EU = 4;                  // edges in flight per group
    int wid  = (blockIdx.x * 256 + threadIdx.x) >> 6;
    int lane = threadIdx.x & 63;
    int fb = lane & (FB - 1);
    int g  = lane / FB;
    int waveCount = gridDim.x * 4;

    for (int nbase = wid * GN; nbase < n; nbase += waveCount * GN) {
        int node = nbase + g;
        bool vn = node < n;
        int beg = vn ? rowptr[node] : 0;
        int end = vn ? rowptr[node + 1] : 0;
        int m = end - beg;

        int mmax = m;
#pragma unroll
        for (int off = FB; off < 64; off <<= 1) {
            int t = __shfl_xor(mmax, off);
            mmax = mmax > t ? mmax : t;
        }

        float acc[8];
#pragma unroll
        for (int k = 0; k < 8; k++) acc[k] = 0.f;

        int cv = 0;
        for (int j0 = 0; j0 < mmax; j0 += EU) {
            if ((j0 & (FB - 1)) == 0) {
                int idx = beg + j0 + fb;
                cv = __builtin_nontemporal_load(&colidx[idx < end ? idx : 0]);
            }
            int s[EU];
#pragma unroll
            for (int u = 0; u < EU; u++) {
                int j = j0 + u;
                int sv = __shfl(cv, g * FB + (j & (FB - 1)));
                s[u] = j < m ? sv : n;             // row n = zero row
            }
            f16x8 v[EU];
#pragma unroll
            for (int u = 0; u < EU; u++)
                v[u] = *(const f16x8*)&h[(size_t)s[u] * D + fb * 8];
#pragma unroll
            for (int u = 0; u < EU; u++) {
#pragma unroll
                for (int k = 0; k < 8; k++)
                    acc[k] += (float)v[u][k];
            }
        }

        if (vn) {
            float nd = ndst[node];
            float bv[8];
            *(float4*)&bv[0] = ((const float4*)bias)[fb * 2];
            *(float4*)&bv[4] = ((const float4*)bias)[fb * 2 + 1];
            float vv[8];
#pragma unroll
            for (int k = 0; k < 8; k++) vv[k] = acc[k] * nd + bv[k];
            if (MODE == 1) {
                f16x8 q;
#pragma unroll
                for (int k = 0; k < 8; k++)
                    q[k] = (_Float16)fast_tanh(vv[k]);
                *(f16x8*)&oq[(size_t)node * D + fb * 8] = q;
            } else {
                *(float4*)&out[(size_t)node * D + fb * 8] = *(float4*)&vv[0];
                *(float4*)&out[(size_t)node * D + fb * 8 + 4] = *(float4*)&vv[4];
            }
        }
    }
}

// ---------------- host ----------------

extern "C" void kernel_launch(void* const* d_in, const int* in_sizes, int n_in,
                              void* d_out, int out_size, void* d_ws, size_t ws_size,
                              hipStream_t stream) {
    const float* features = (const float*)d_in[0];
    const int* edges      = (const int*)d_in[1];
    const float* W0 = (const float*)d_in[2]; const float* b0 = (const float*)d_in[3];
    const float* W1 = (const float*)d_in[4]; const float* b1 = (const float*)d_in[5];
    const float* W2 = (const float*)d_in[6]; const float* b2 = (const float*)d_in[7];
    const float* W3 = (const float*)d_in[8]; const float* b3 = (const float*)d_in[9];
    float* out = (float*)d_out;

    const int N = in_sizes[0] / 128;
    const int E = in_sizes[1] / 2;
    const int* src = edges;
    const int* dst = edges + E;
    const int K = (N + 63) >> 6;
    const int chunk = (E + CB - 1) / CB;
    const int scanN = K * CB;
    const int n2 = 2 * scanN;
    const int numTiles = (n2 + SCAN_TILE - 1) / SCAN_TILE;
    const size_t dynLds = (size_t)2 * K * sizeof(int);

    char* p = (char*)d_ws;
    _Float16* bufH         = (_Float16*)p;       p += (size_t)N * 128 * 4;  // fp32-sized slot; row N = zero row
    _Float16* xq           = (_Float16*)p;       p += (size_t)(N + 1) * 128 * 2;
    char*     xspare       = p;                  p += (size_t)(N + 1) * 128 * 2;  // transient-sort spill
    int*   rowptr = (int*)p;   p += (((size_t)(N + 1) * 4 + 15) / 16) * 16;
    int*   colidx = (int*)p;   p += (size_t)E * 4;
    float* nsrc   = (float*)p; p += (size_t)N * 4;
    float* ndst   = (float*)p; p += (size_t)N * 4;
    int*   tilesum= (int*)p;   p += (((size_t)(numTiles + 1) * 4 + 15) / 16) * 16;
    unsigned short* wt0h = (unsigned short*)p; p += 16384 * 2;
    unsigned short* wt0l = (unsigned short*)p; p += 16384 * 2;
    unsigned short* wt1h = (unsigned short*)p; p += 16384 * 2;
    unsigned short* wt1l = (unsigned short*)p; p += 16384 * 2;
    unsigned short* wt2h = (unsigned short*)p; p += 16384 * 2;
    unsigned short* wt2l = (unsigned short*)p; p += 16384 * 2;
    unsigned short* wt3h = (unsigned short*)p; p += 8192 * 2;
    unsigned short* wt3l = (unsigned short*)p; p += 8192 * 2;

    // transient counting-sort buffers aliased into xq/xspare region
    char* q = (char*)xq;
    int* sortedAll = (int*)q; q += (size_t)2 * E * 4;
    int* gH        = (int*)q; q += (size_t)n2 * 4;
    int* gHS       = (int*)q; q += (size_t)(n2 + 1) * 4;
    (void)xspare;

    k_prepW_all<<<224, 256, 0, stream>>>(W0, W1, W2, W3, wt0h, wt0l, wt1h, wt1l,
                                         wt2h, wt2l, wt3h, wt3l);
    k_bucket_hist<<<CB, 256, dynLds, stream>>>(src, dst, gH, E, K, scanN, chunk);
    k_scan_partial<<<numTiles, 256, 0, stream>>>(gH, tilesum, n2);
    k_scan_tiles<<<1, 64, 0, stream>>>(tilesum, gHS, numTiles, n2);
    k_scan_final<<<numTiles, 256, 0, stream>>>(gH, tilesum, gHS, n2);
    k_bucket_scatter<<<CB, 256, dynLds, stream>>>(src, dst, gHS, sortedAll, E, K, scanN, chunk);
    k_fine<<<2 * K, 256, 0, stream>>>(sortedAll, gHS, rowptr, colidx, nsrc, ndst, E, K, scanN, N);

    int gblk = (N + 63) / 64;
    int ablk128 = (N + 15) / 16;   // 4 waves/block x 4 nodes/wave
    int ablk64  = (N + 31) / 32;   // 4 waves/block x 8 nodes/wave
    k_gemm_hyb<128, 0><<<gblk, 256, 0, stream>>>(features, nullptr, wt0h, wt0l, nsrc, bufH, N);
    k_aggregate<128, 1><<<ablk128, 256, 0, stream>>>(bufH, rowptr, colidx, ndst, b0, nullptr, xq, N);
    k_gemm_hyb<128, 1><<<gblk, 256, 0, stream>>>(nullptr, xq, wt1h, wt1l, nsrc, bufH, N);
    k_aggregate<128, 1><<<ablk128, 256, 0, stream>>>(bufH, rowptr, colidx, ndst, b1, nullptr, xq, N);
    k_gemm_hyb<128, 1><<<gblk, 256, 0, stream>>>(nullptr, xq, wt2h, wt2l, nsrc, bufH, N);
    k_aggregate<128, 1><<<ablk128, 256, 0, stream>>>(bufH, rowptr, colidx, ndst, b2, nullptr, xq, N);
    k_gemm_hyb<64, 1><<<gblk, 256, 0, stream>>>(nullptr, xq, wt3h, wt3l, nsrc, bufH, N);
    k_aggregate<64, 0><<<ablk64, 256, 0, stream>>>(bufH, rowptr, colidx, ndst, b3, out, nullptr, N);
}

// Round 9
// 493.943 us; speedup vs baseline: 1.0794x; 1.0405x over previous
//
#include <hip/hip_runtime.h>
#include <cmath>

typedef __attribute__((ext_vector_type(8))) short bf16x8;
typedef __attribute__((ext_vector_type(8))) _Float16 f16x8;
typedef __attribute__((ext_vector_type(4))) float f32x4;

__device__ inline unsigned short f2bf_rne(float f) {
    unsigned int u = __float_as_uint(f);
    unsigned int r = (u + 0x7FFFu + ((u >> 16) & 1u)) >> 16;
    return (unsigned short)r;
}
__device__ inline float bf2f(unsigned short h) {
    return __uint_as_float(((unsigned int)h) << 16);
}

// fast tanh: (t-1)/(t+1), t = exp2(2x*log2e). ~7 VALU + 2 trans vs libm ~20.
__device__ inline float fast_tanh(float x) {
    float e = x * 2.8853900817779268f;            // 2*log2(e)
    e = fminf(fmaxf(e, -126.f), 126.f);
    float t = __builtin_amdgcn_exp2f(e);
    return (t - 1.0f) * __builtin_amdgcn_rcpf(t + 1.0f);
}

// ---------------- CSR build via two-level counting sort ------------------------
// R19: (a) XCD-contiguous chunk swizzle in hist/scatter — consecutive chunks
// (which share sortedAll/gH cache lines at segment boundaries) are processed
// by same-XCD blocks (XCD = bid%8 round-robin), so boundary RMW stays in one
// L2 instead of ping-ponging across dies (R6's lesson, line-granularity form).
// (b) k_fine stages the dst bucket in LDS (<=3072 entries) — one global read
// instead of two. Outputs bit-identical; pure relabeling + read-path change.
// Packing (dlocal<<17|src) requires N <= 2^17.

constexpr int CB = 256;

__global__ __launch_bounds__(256) void k_bucket_hist(const int* __restrict__ src,
                                                     const int* __restrict__ dst,
                                                     int* __restrict__ gH,
                                                     int E, int K, int scanN, int chunk) {
    extern __shared__ int lds[];
    int* hd = lds; int* hs = lds + K;
    int cb = ((blockIdx.x & 7) * (CB >> 3)) + (blockIdx.x >> 3);   // XCD-contiguous chunk
    for (int i = threadIdx.x; i < 2 * K; i += 256) lds[i] = 0;
    __syncthreads();
    int lo = cb * chunk;
    int hi = lo + chunk; if (hi > E) hi = E;
    for (int i = lo + threadIdx.x; i < hi; i += 256) {
        atomicAdd(&hd[dst[i] >> 6], 1);
        atomicAdd(&hs[src[i] >> 6], 1);
    }
    __syncthreads();
    for (int k = threadIdx.x; k < K; k += 256) {
        gH[(size_t)k * CB + cb] = hd[k];
        gH[(size_t)(scanN + k * CB) + cb] = hs[k];
    }
}

__global__ __launch_bounds__(256) void k_bucket_scatter(const int* __restrict__ src,
                                                        const int* __restrict__ dst,
                                                        const int* __restrict__ gHS,
                                                        int* __restrict__ sortedAll,
                                                        int E, int K, int scanN, int chunk) {
    extern __shared__ int lds[];
    int* bd = lds; int* bs = lds + K;
    int cb = ((blockIdx.x & 7) * (CB >> 3)) + (blockIdx.x >> 3);   // XCD-contiguous chunk
    for (int k = threadIdx.x; k < K; k += 256) {
        bd[k] = gHS[(size_t)k * CB + cb];
        bs[k] = gHS[(size_t)(scanN + k * CB) + cb];
    }
    __syncthreads();
    int lo = cb * chunk;
    int hi = lo + chunk; if (hi > E) hi = E;
    for (int i = lo + threadIdx.x; i < hi; i += 256) {
        int d = dst[i], s = src[i];
        int pd = atomicAdd(&bd[d >> 6], 1);
        sortedAll[pd] = ((d & 63) << 17) | s;
        int ps = atomicAdd(&bs[s >> 6], 1);
        sortedAll[ps] = s;
    }
}

constexpr int FINE_CAP = 3072;

__global__ __launch_bounds__(256) void k_fine(const int* __restrict__ sortedAll,
                                              const int* __restrict__ gHS,
                                              int* __restrict__ rowptr,
                                              int* __restrict__ colidx,
                                              float* __restrict__ nsrc,
                                              float* __restrict__ ndst,
                                              int E, int K, int scanN, int N) {
    __shared__ int cnt[64], excl[64], rank[64];
    __shared__ int stage[FINE_CAP];
    int kb = blockIdx.x;
    bool isDst = kb < K;
    int k = isDst ? kb : kb - K;
    int bstart, bend;
    if (isDst) {
        bstart = gHS[(size_t)k * CB];
        bend = (k + 1 < K) ? gHS[(size_t)(k + 1) * CB] : E;
    } else {
        bstart = gHS[(size_t)(scanN + k * CB)];
        bend = (k + 1 < K) ? gHS[(size_t)(scanN + (k + 1) * CB)] : 2 * E;
    }
    int len = bend - bstart;
    bool useLds = isDst && (len <= FINE_CAP);
    if (threadIdx.x < 64) { cnt[threadIdx.x] = 0; rank[threadIdx.x] = 0; }
    if (useLds) {
        for (int i = threadIdx.x; i < len; i += 256)
            stage[i] = sortedAll[bstart + i];
    }
    __syncthreads();
    if (isDst) {
        if (useLds) {
            for (int i = threadIdx.x; i < len; i += 256)
                atomicAdd(&cnt[stage[i] >> 17], 1);
        } else {
            for (int i = bstart + threadIdx.x; i < bend; i += 256)
                atomicAdd(&cnt[sortedAll[i] >> 17], 1);
        }
    } else {
        for (int i = bstart + threadIdx.x; i < bend; i += 256)
            atomicAdd(&cnt[sortedAll[i] & 63], 1);
    }
    __syncthreads();
    if (isDst) {
        if (threadIdx.x == 0) {
            int r = 0;
            for (int j = 0; j < 64; j++) { excl[j] = r; r += cnt[j]; }
        }
        __syncthreads();
        int node0 = k << 6;
        if (threadIdx.x < 64) {
            int node = node0 + threadIdx.x;
            if (node < N) {
                rowptr[node] = bstart + excl[threadIdx.x];
                int c = cnt[threadIdx.x];
                ndst[node] = c > 0 ? rsqrtf((float)c) : 0.f;
            }
        }
        if (k == 0 && threadIdx.x == 0) rowptr[N] = E;
        if (useLds) {
            for (int i = threadIdx.x; i < len; i += 256) {
                int v = stage[i];
                int n = v >> 17;
                int r = atomicAdd(&rank[n], 1);
                colidx[bstart + excl[n] + r] = v & 0x1FFFF;
            }
        } else {
            for (int i = bstart + threadIdx.x; i < bend; i += 256) {
                int v = sortedAll[i];
                int n = v >> 17;
                int r = atomicAdd(&rank[n], 1);
                colidx[bstart + excl[n] + r] = v & 0x1FFFF;
            }
        }
    } else {
        int node = (k << 6) + threadIdx.x;
        if (threadIdx.x < 64 && node < N) {
            int c = cnt[threadIdx.x];
            nsrc[node] = c > 0 ? rsqrtf((float)c) : 0.f;
        }
    }
}

// W (fp32, k-major [k][n]) -> Wt hi/lo, n-major [n][k], all 4 layers.
// Layer 0: bf16 pair (GEMM0 consumes fp32 features via bf16 path).
// Layers 1-3: fp16 pair (GEMM consumes fp16 x via f16 MFMA, 2 MFMAs/step).
__global__ void k_prepW_all(const float* __restrict__ W0, const float* __restrict__ W1,
                            const float* __restrict__ W2, const float* __restrict__ W3,
                            unsigned short* __restrict__ h0, unsigned short* __restrict__ l0,
                            unsigned short* __restrict__ h1, unsigned short* __restrict__ l1,
                            unsigned short* __restrict__ h2, unsigned short* __restrict__ l2,
                            unsigned short* __restrict__ h3, unsigned short* __restrict__ l3) {
    int i = blockIdx.x * 256 + threadIdx.x;
    const float* W; unsigned short* wh; unsigned short* wl; int N; int base; bool bf;
    if      (i < 16384) { W = W0; wh = h0; wl = l0; N = 128; base = i;         bf = true;  }
    else if (i < 32768) { W = W1; wh = h1; wl = l1; N = 128; base = i - 16384; bf = false; }
    else if (i < 49152) { W = W2; wh = h2; wl = l2; N = 128; base = i - 32768; bf = false; }
    else if (i < 57344) { W = W3; wh = h3; wl = l3; N = 64;  base = i - 49152; bf = false; }
    else return;
    int n = base >> 7, k = base & 127;
    float w = W[k * N + n];
    if (bf) {
        unsigned short hb = f2bf_rne(w);
        unsigned short lb = f2bf_rne(w - bf2f(hb));
        wh[base] = hb; wl[base] = lb;
    } else {
        union { _Float16 f; unsigned short u; } H, L;
        H.f = (_Float16)w;
        L.f = (_Float16)(w - (float)H.f);
        wh[base] = H.u; wl[base] = L.u;
    }
}

// ---------------- device-wide exclusive scan (tile = 2048) ----------------

constexpr int SCAN_TILE = 2048;

__global__ __launch_bounds__(256) void k_scan_partial(const int* __restrict__ deg,
                                                      int* __restrict__ tilesum, int n) {
    __shared__ int red[256];
    int base = blockIdx.x * SCAN_TILE;
    int s = 0;
    for (int i = threadIdx.x; i < SCAN_TILE; i += 256) {
        int idx = base + i;
        if (idx < n) s += deg[idx];
    }
    red[threadIdx.x] = s;
    __syncthreads();
    for (int off = 128; off > 0; off >>= 1) {
        if (threadIdx.x < off) red[threadIdx.x] += red[threadIdx.x + off];
        __syncthreads();
    }
    if (threadIdx.x == 0) tilesum[blockIdx.x] = red[0];
}

__global__ void k_scan_tiles(int* __restrict__ tilesum, int* __restrict__ outArr,
                             int numTiles, int n) {
    if (threadIdx.x == 0 && blockIdx.x == 0) {
        int acc = 0;
        for (int i = 0; i < numTiles; i++) { int v = tilesum[i]; tilesum[i] = acc; acc += v; }
        outArr[n] = acc;
    }
}

__global__ __launch_bounds__(256) void k_scan_final(const int* __restrict__ deg,
                                                    const int* __restrict__ tilesum,
                                                    int* __restrict__ outArr, int n) {
    __shared__ int red[256];
    int base = blockIdx.x * SCAN_TILE;
    int lo = base + threadIdx.x * 8;
    int v[8]; int s = 0;
#pragma unroll
    for (int j = 0; j < 8; j++) {
        int idx = lo + j;
        v[j] = (idx < n) ? deg[idx] : 0;
        s += v[j];
    }
    red[threadIdx.x] = s;
    __syncthreads();
    for (int off = 1; off < 256; off <<= 1) {
        int x = red[threadIdx.x];
        int add = (threadIdx.x >= off) ? red[threadIdx.x - off] : 0;
        __syncthreads();
        red[threadIdx.x] = x + add;
        __syncthreads();
    }
    int excl = tilesum[blockIdx.x] + (threadIdx.x ? red[threadIdx.x - 1] : 0);
#pragma unroll
    for (int j = 0; j < 8; j++) {
        int idx = lo + j;
        if (idx < n) outArr[idx] = excl;
        excl += v[j];
    }
}

// ---------------- GEMM: B in LDS, A direct from global (R11/R15 form) ----------
// SRC==0: A = fp32 features -> bf16 hi/lo split, B = bf16 hi/lo, 3 bf16 MFMAs.
// SRC==1: A = fp16 x (single), B = fp16 hi/lo, 2 f16 MFMAs.
// RT=1 only: R6/R7's RT=2 regressed (~+5us/GEMM, suspected VGPR-cliff).
// Writes fp16 h + a ZERO row at h[nrows*DOUT] for masked aggregate slots.

template <int DOUT, int SRC>
__global__ __launch_bounds__(256) void k_gemm_hyb(
        const float* __restrict__ xf, const _Float16* __restrict__ xq,
        const unsigned short* __restrict__ wth, const unsigned short* __restrict__ wtl,
        const float* __restrict__ nsrc, _Float16* __restrict__ h, int nrows) {
    constexpr int NT = DOUT / 16;    // n-tiles per wave (8 or 4), wave owns 16 rows x DOUT
    constexpr int LDK = 72;          // 64 k-half + 8 pad (16B-aligned rows)
    __shared__ unsigned short Bh[DOUT * LDK], Bl[DOUT * LDK];

    int tid = threadIdx.x;
    int lane = tid & 63;
    int wv = tid >> 6;
    int quad = lane >> 4, l16 = lane & 15;
    int r0 = blockIdx.x * 64 + wv * 16;
    int rowA = r0 + l16; if (rowA >= nrows) rowA = nrows - 1;   // clamped load row

    // zero row for the aggregate's masked edge slots
    if (blockIdx.x == 0 && tid < DOUT / 8) {
        f32x4 z = {0.f, 0.f, 0.f, 0.f};
        *(f32x4*)((char*)h + ((size_t)nrows * DOUT + tid * 8) * 2) = z;
    }

    f32x4 acc[NT];
#pragma unroll
    for (int nt = 0; nt < NT; nt++) acc[nt] = (f32x4){0.f, 0.f, 0.f, 0.f};

    for (int kh = 0; kh < 2; kh++) {
        if (kh) __syncthreads();
        // stage B half: DOUT n-rows x 64 k
        for (int i = tid; i < DOUT * 16; i += 256) {
            int n = i >> 4, kb = i & 15;
            int koff = kh * 64 + kb * 4;
            *(ushort4*)&Bh[n * LDK + kb * 4] = *(const ushort4*)&wth[n * 128 + koff];
            *(ushort4*)&Bl[n * LDK + kb * 4] = *(const ushort4*)&wtl[n * 128 + koff];
        }
        __syncthreads();

#pragma unroll
        for (int kq = 0; kq < 2; kq++) {
            int koA = kh * 64 + kq * 32 + quad * 8;   // global k offset for A
            int koB = kq * 32 + quad * 8;             // LDS offset within half
            if (SRC == 0) {
                const float* xp = &xf[(size_t)rowA * 128 + koA];
                f32x4 x0 = *(const f32x4*)xp;
                f32x4 x1 = *(const f32x4*)(xp + 4);
                union { bf16x8 v; unsigned short u[8]; } H, L;
                float xs[8] = {x0[0], x0[1], x0[2], x0[3], x1[0], x1[1], x1[2], x1[3]};
#pragma unroll
                for (int j = 0; j < 8; j++) {
                    H.u[j] = f2bf_rne(xs[j]);
                    L.u[j] = f2bf_rne(xs[j] - bf2f(H.u[j]));
                }
                bf16x8 ah = H.v, al = L.v;
#pragma unroll
                for (int nt = 0; nt < NT; nt++) {
                    int n = nt * 16 + l16;
                    bf16x8 bh = *(const bf16x8*)&Bh[n * LDK + koB];
                    bf16x8 bl = *(const bf16x8*)&Bl[n * LDK + koB];
                    acc[nt] = __builtin_amdgcn_mfma_f32_16x16x32_bf16(ah, bh, acc[nt], 0, 0, 0);
                    acc[nt] = __builtin_amdgcn_mfma_f32_16x16x32_bf16(ah, bl, acc[nt], 0, 0, 0);
                    acc[nt] = __builtin_amdgcn_mfma_f32_16x16x32_bf16(al, bh, acc[nt], 0, 0, 0);
                }
            } else {
                f16x8 aq = *(const f16x8*)&xq[(size_t)rowA * 128 + koA];
#pragma unroll
                for (int nt = 0; nt < NT; nt++) {
                    int n = nt * 16 + l16;
                    f16x8 bh = *(const f16x8*)&Bh[n * LDK + koB];
                    f16x8 bl = *(const f16x8*)&Bl[n * LDK + koB];
                    acc[nt] = __builtin_amdgcn_mfma_f32_16x16x32_f16(aq, bh, acc[nt], 0, 0, 0);
                    acc[nt] = __builtin_amdgcn_mfma_f32_16x16x32_f16(aq, bl, acc[nt], 0, 0, 0);
                }
            }
        }
    }

#pragma unroll
    for (int r = 0; r < 4; r++) {
        int row = r0 + quad * 4 + r;
        if (row < nrows) {
            float nm = nsrc[row];
#pragma unroll
            for (int nt = 0; nt < NT; nt++)
                h[(size_t)row * DOUT + nt * 16 + l16] = (_Float16)(acc[nt][r] * nm);
        }
    }
}

// ---------------- aggregation: 16-lane-group-per-node (R2 form, anchor) -------
// At the ~3.5 TB/s scattered-line ceiling (R0/R2/R3/R4 all converge there).
// colidx reads non-temporal (read-once stream); x/out writes REGULAR.

template <int D, int MODE>
__global__ __launch_bounds__(256) void k_aggregate(const _Float16* __restrict__ h,
                                                   const int* __restrict__ rowptr,
                                                   const int* __restrict__ colidx,
                                                   const float* __restrict__ ndst,
                                                   const float* __restrict__ bias,
                                                   float* __restrict__ out,
                                                   _Float16* __restrict__ oq,
                                                   int n) {
    constexpr int FB = D / 8;              // lanes per node row (16B fp16 each)
    constexpr int GN = 64 / FB;            // nodes per wave
    constexpr int EU = 4;                  // edges in flight per group
    int wid  = (blockIdx.x * 256 + threadIdx.x) >> 6;
    int lane = threadIdx.x & 63;
    int fb = lane & (FB - 1);
    int g  = lane / FB;
    int waveCount = gridDim.x * 4;

    for (int nbase = wid * GN; nbase < n; nbase += waveCount * GN) {
        int node = nbase + g;
        bool vn = node < n;
        int beg = vn ? rowptr[node] : 0;
        int end = vn ? rowptr[node + 1] : 0;
        int m = end - beg;

        int mmax = m;
#pragma unroll
        for (int off = FB; off < 64; off <<= 1) {
            int t = __shfl_xor(mmax, off);
            mmax = mmax > t ? mmax : t;
        }

        float acc[8];
#pragma unroll
        for (int k = 0; k < 8; k++) acc[k] = 0.f;

        int cv = 0;
        for (int j0 = 0; j0 < mmax; j0 += EU) {
            if ((j0 & (FB - 1)) == 0) {
                int idx = beg + j0 + fb;
                cv = __builtin_nontemporal_load(&colidx[idx < end ? idx : 0]);
            }
            int s[EU];
#pragma unroll
            for (int u = 0; u < EU; u++) {
                int j = j0 + u;
                int sv = __shfl(cv, g * FB + (j & (FB - 1)));
                s[u] = j < m ? sv : n;             // row n = zero row
            }
            f16x8 v[EU];
#pragma unroll
            for (int u = 0; u < EU; u++)
                v[u] = *(const f16x8*)&h[(size_t)s[u] * D + fb * 8];
#pragma unroll
            for (int u = 0; u < EU; u++) {
#pragma unroll
                for (int k = 0; k < 8; k++)
                    acc[k] += (float)v[u][k];
            }
        }

        if (vn) {
            float nd = ndst[node];
            float bv[8];
            *(float4*)&bv[0] = ((const float4*)bias)[fb * 2];
            *(float4*)&bv[4] = ((const float4*)bias)[fb * 2 + 1];
            float vv[8];
#pragma unroll
            for (int k = 0; k < 8; k++) vv[k] = acc[k] * nd + bv[k];
            if (MODE == 1) {
                f16x8 q;
#pragma unroll
                for (int k = 0; k < 8; k++)
                    q[k] = (_Float16)fast_tanh(vv[k]);
                *(f16x8*)&oq[(size_t)node * D + fb * 8] = q;
            } else {
                *(float4*)&out[(size_t)node * D + fb * 8] = *(float4*)&vv[0];
                *(float4*)&out[(size_t)node * D + fb * 8 + 4] = *(float4*)&vv[4];
            }
        }
    }
}

// ---------------- host ----------------

extern "C" void kernel_launch(void* const* d_in, const int* in_sizes, int n_in,
                              void* d_out, int out_size, void* d_ws, size_t ws_size,
                              hipStream_t stream) {
    const float* features = (const float*)d_in[0];
    const int* edges      = (const int*)d_in[1];
    const float* W0 = (const float*)d_in[2]; const float* b0 = (const float*)d_in[3];
    const float* W1 = (const float*)d_in[4]; const float* b1 = (const float*)d_in[5];
    const float* W2 = (const float*)d_in[6]; const float* b2 = (const float*)d_in[7];
    const float* W3 = (const float*)d_in[8]; const float* b3 = (const float*)d_in[9];
    float* out = (float*)d_out;

    const int N = in_sizes[0] / 128;
    const int E = in_sizes[1] / 2;
    const int* src = edges;
    const int* dst = edges + E;
    const int K = (N + 63) >> 6;
    const int chunk = (E + CB - 1) / CB;
    const int scanN = K * CB;
    const int n2 = 2 * scanN;
    const int numTiles = (n2 + SCAN_TILE - 1) / SCAN_TILE;
    const size_t dynLds = (size_t)2 * K * sizeof(int);

    char* p = (char*)d_ws;
    _Float16* bufH         = (_Float16*)p;       p += (size_t)N * 128 * 4;  // fp32-sized slot; row N = zero row
    _Float16* xq           = (_Float16*)p;       p += (size_t)(N + 1) * 128 * 2;
    char*     xspare       = p;                  p += (size_t)(N + 1) * 128 * 2;  // transient-sort spill
    int*   rowptr = (int*)p;   p += (((size_t)(N + 1) * 4 + 15) / 16) * 16;
    int*   colidx = (int*)p;   p += (size_t)E * 4;
    float* nsrc   = (float*)p; p += (size_t)N * 4;
    float* ndst   = (float*)p; p += (size_t)N * 4;
    int*   tilesum= (int*)p;   p += (((size_t)(numTiles + 1) * 4 + 15) / 16) * 16;
    unsigned short* wt0h = (unsigned short*)p; p += 16384 * 2;
    unsigned short* wt0l = (unsigned short*)p; p += 16384 * 2;
    unsigned short* wt1h = (unsigned short*)p; p += 16384 * 2;
    unsigned short* wt1l = (unsigned short*)p; p += 16384 * 2;
    unsigned short* wt2h = (unsigned short*)p; p += 16384 * 2;
    unsigned short* wt2l = (unsigned short*)p; p += 16384 * 2;
    unsigned short* wt3h = (unsigned short*)p; p += 8192 * 2;
    unsigned short* wt3l = (unsigned short*)p; p += 8192 * 2;

    // transient counting-sort buffers aliased into xq/xspare region
    char* q = (char*)xq;
    int* sortedAll = (int*)q; q += (size_t)2 * E * 4;
    int* gH        = (int*)q; q += (size_t)n2 * 4;
    int* gHS       = (int*)q; q += (size_t)(n2 + 1) * 4;
    (void)xspare;

    k_prepW_all<<<224, 256, 0, stream>>>(W0, W1, W2, W3, wt0h, wt0l, wt1h, wt1l,
                                         wt2h, wt2l, wt3h, wt3l);
    k_bucket_hist<<<CB, 256, dynLds, stream>>>(src, dst, gH, E, K, scanN, chunk);
    k_scan_partial<<<numTiles, 256, 0, stream>>>(gH, tilesum, n2);
    k_scan_tiles<<<1, 64, 0, stream>>>(tilesum, gHS, numTiles, n2);
    k_scan_final<<<numTiles, 256, 0, stream>>>(gH, tilesum, gHS, n2);
    k_bucket_scatter<<<CB, 256, dynLds, stream>>>(src, dst, gHS, sortedAll, E, K, scanN, chunk);
    k_fine<<<2 * K, 256, 0, stream>>>(sortedAll, gHS, rowptr, colidx, nsrc, ndst, E, K, scanN, N);

    int gblk = (N + 63) / 64;
    int ablk128 = (N + 15) / 16;   // 4 waves/block x 4 nodes/wave
    int ablk64  = (N + 31) / 32;   // 4 waves/block x 8 nodes/wave
    k_gemm_hyb<128, 0><<<gblk, 256, 0, stream>>>(features, nullptr, wt0h, wt0l, nsrc, bufH, N);
    k_aggregate<128, 1><<<ablk128, 256, 0, stream>>>(bufH, rowptr, colidx, ndst, b0, nullptr, xq, N);
    k_gemm_hyb<128, 1><<<gblk, 256, 0, stream>>>(nullptr, xq, wt1h, wt1l, nsrc, bufH, N);
    k_aggregate<128, 1><<<ablk128, 256, 0, stream>>>(bufH, rowptr, colidx, ndst, b1, nullptr, xq, N);
    k_gemm_hyb<128, 1><<<gblk, 256, 0, stream>>>(nullptr, xq, wt2h, wt2l, nsrc, bufH, N);
    k_aggregate<128, 1><<<ablk128, 256, 0, stream>>>(bufH, rowptr, colidx, ndst, b2, nullptr, xq, N);
    k_gemm_hyb<64, 1><<<gblk, 256, 0, stream>>>(nullptr, xq, wt3h, wt3l, nsrc, bufH, N);
    k_aggregate<64, 0><<<ablk64, 256, 0, stream>>>(bufH, rowptr, colidx, ndst, b3, out, nullptr, N);
}

// Round 10
// 450.027 us; speedup vs baseline: 1.1848x; 1.0976x over previous
//
#include <hip/hip_runtime.h>
#include <cmath>

typedef __attribute__((ext_vector_type(8))) short bf16x8;
typedef __attribute__((ext_vector_type(8))) _Float16 f16x8;
typedef __attribute__((ext_vector_type(4))) float f32x4;

__device__ inline unsigned short f2bf_rne(float f) {
    unsigned int u = __float_as_uint(f);
    unsigned int r = (u + 0x7FFFu + ((u >> 16) & 1u)) >> 16;
    return (unsigned short)r;
}
__device__ inline float bf2f(unsigned short h) {
    return __uint_as_float(((unsigned int)h) << 16);
}

// fast tanh: (t-1)/(t+1), t = exp2(2x*log2e). ~7 VALU + 2 trans vs libm ~20.
__device__ inline float fast_tanh(float x) {
    float e = x * 2.8853900817779268f;            // 2*log2(e)
    e = fminf(fmaxf(e, -126.f), 126.f);
    float t = __builtin_amdgcn_exp2f(e);
    return (t - 1.0f) * __builtin_amdgcn_rcpf(t + 1.0f);
}

// ---------------- CSR build via two-level counting sort ------------------------
// R19: XCD-contiguous chunk swizzle (hist/scatter) + LDS-staged k_fine. R20:
// dispatch-count reduction (15->13), bit-identical: weight prep fused into the
// hist kernel as extra blocks; the serial k_scan_tiles kernel deleted (each
// scan_final block sums its own tilesum prefix; the gHS[n2] sentinel was dead).
// Packing (dlocal<<17|src) requires N <= 2^17.

constexpr int CB = 256;
constexpr int PREPB = 224;   // prep blocks appended after the CB hist blocks

__global__ __launch_bounds__(256) void k_prep_hist(
        const int* __restrict__ src, const int* __restrict__ dst,
        int* __restrict__ gH, int E, int K, int scanN, int chunk,
        const float* __restrict__ W0, const float* __restrict__ W1,
        const float* __restrict__ W2, const float* __restrict__ W3,
        unsigned short* __restrict__ h0, unsigned short* __restrict__ l0,
        unsigned short* __restrict__ h1, unsigned short* __restrict__ l1,
        unsigned short* __restrict__ h2, unsigned short* __restrict__ l2,
        unsigned short* __restrict__ h3, unsigned short* __restrict__ l3) {
    if (blockIdx.x < CB) {
        extern __shared__ int lds[];
        int* hd = lds; int* hs = lds + K;
        int cb = ((blockIdx.x & 7) * (CB >> 3)) + (blockIdx.x >> 3);   // XCD-contiguous chunk
        for (int i = threadIdx.x; i < 2 * K; i += 256) lds[i] = 0;
        __syncthreads();
        int lo = cb * chunk;
        int hi = lo + chunk; if (hi > E) hi = E;
        for (int i = lo + threadIdx.x; i < hi; i += 256) {
            atomicAdd(&hd[dst[i] >> 6], 1);
            atomicAdd(&hs[src[i] >> 6], 1);
        }
        __syncthreads();
        for (int k = threadIdx.x; k < K; k += 256) {
            gH[(size_t)k * CB + cb] = hd[k];
            gH[(size_t)(scanN + k * CB) + cb] = hs[k];
        }
    } else {
        int i = (blockIdx.x - CB) * 256 + threadIdx.x;
        const float* W; unsigned short* wh; unsigned short* wl; int N; int base; bool bf;
        if      (i < 16384) { W = W0; wh = h0; wl = l0; N = 128; base = i;         bf = true;  }
        else if (i < 32768) { W = W1; wh = h1; wl = l1; N = 128; base = i - 16384; bf = false; }
        else if (i < 49152) { W = W2; wh = h2; wl = l2; N = 128; base = i - 32768; bf = false; }
        else if (i < 57344) { W = W3; wh = h3; wl = l3; N = 64;  base = i - 49152; bf = false; }
        else return;
        int n = base >> 7, k = base & 127;
        float w = W[k * N + n];
        if (bf) {
            unsigned short hb = f2bf_rne(w);
            unsigned short lb = f2bf_rne(w - bf2f(hb));
            wh[base] = hb; wl[base] = lb;
        } else {
            union { _Float16 f; unsigned short u; } H, L;
            H.f = (_Float16)w;
            L.f = (_Float16)(w - (float)H.f);
            wh[base] = H.u; wl[base] = L.u;
        }
    }
}

__global__ __launch_bounds__(256) void k_bucket_scatter(const int* __restrict__ src,
                                                        const int* __restrict__ dst,
                                                        const int* __restrict__ gHS,
                                                        int* __restrict__ sortedAll,
                                                        int E, int K, int scanN, int chunk) {
    extern __shared__ int lds[];
    int* bd = lds; int* bs = lds + K;
    int cb = ((blockIdx.x & 7) * (CB >> 3)) + (blockIdx.x >> 3);   // XCD-contiguous chunk
    for (int k = threadIdx.x; k < K; k += 256) {
        bd[k] = gHS[(size_t)k * CB + cb];
        bs[k] = gHS[(size_t)(scanN + k * CB) + cb];
    }
    __syncthreads();
    int lo = cb * chunk;
    int hi = lo + chunk; if (hi > E) hi = E;
    for (int i = lo + threadIdx.x; i < hi; i += 256) {
        int d = dst[i], s = src[i];
        int pd = atomicAdd(&bd[d >> 6], 1);
        sortedAll[pd] = ((d & 63) << 17) | s;
        int ps = atomicAdd(&bs[s >> 6], 1);
        sortedAll[ps] = s;
    }
}

constexpr int FINE_CAP = 3072;

__global__ __launch_bounds__(256) void k_fine(const int* __restrict__ sortedAll,
                                              const int* __restrict__ gHS,
                                              int* __restrict__ rowptr,
                                              int* __restrict__ colidx,
                                              float* __restrict__ nsrc,
                                              float* __restrict__ ndst,
                                              int E, int K, int scanN, int N) {
    __shared__ int cnt[64], excl[64], rank[64];
    __shared__ int stage[FINE_CAP];
    int kb = blockIdx.x;
    bool isDst = kb < K;
    int k = isDst ? kb : kb - K;
    int bstart, bend;
    if (isDst) {
        bstart = gHS[(size_t)k * CB];
        bend = (k + 1 < K) ? gHS[(size_t)(k + 1) * CB] : E;
    } else {
        bstart = gHS[(size_t)(scanN + k * CB)];
        bend = (k + 1 < K) ? gHS[(size_t)(scanN + (k + 1) * CB)] : 2 * E;
    }
    int len = bend - bstart;
    bool useLds = isDst && (len <= FINE_CAP);
    if (threadIdx.x < 64) { cnt[threadIdx.x] = 0; rank[threadIdx.x] = 0; }
    if (useLds) {
        for (int i = threadIdx.x; i < len; i += 256)
            stage[i] = sortedAll[bstart + i];
    }
    __syncthreads();
    if (isDst) {
        if (useLds) {
            for (int i = threadIdx.x; i < len; i += 256)
                atomicAdd(&cnt[stage[i] >> 17], 1);
        } else {
            for (int i = bstart + threadIdx.x; i < bend; i += 256)
                atomicAdd(&cnt[sortedAll[i] >> 17], 1);
        }
    } else {
        for (int i = bstart + threadIdx.x; i < bend; i += 256)
            atomicAdd(&cnt[sortedAll[i] & 63], 1);
    }
    __syncthreads();
    if (isDst) {
        if (threadIdx.x == 0) {
            int r = 0;
            for (int j = 0; j < 64; j++) { excl[j] = r; r += cnt[j]; }
        }
        __syncthreads();
        int node0 = k << 6;
        if (threadIdx.x < 64) {
            int node = node0 + threadIdx.x;
            if (node < N) {
                rowptr[node] = bstart + excl[threadIdx.x];
                int c = cnt[threadIdx.x];
                ndst[node] = c > 0 ? rsqrtf((float)c) : 0.f;
            }
        }
        if (k == 0 && threadIdx.x == 0) rowptr[N] = E;
        if (useLds) {
            for (int i = threadIdx.x; i < len; i += 256) {
                int v = stage[i];
                int n = v >> 17;
                int r = atomicAdd(&rank[n], 1);
                colidx[bstart + excl[n] + r] = v & 0x1FFFF;
            }
        } else {
            for (int i = bstart + threadIdx.x; i < bend; i += 256) {
                int v = sortedAll[i];
                int n = v >> 17;
                int r = atomicAdd(&rank[n], 1);
                colidx[bstart + excl[n] + r] = v & 0x1FFFF;
            }
        }
    } else {
        int node = (k << 6) + threadIdx.x;
        if (threadIdx.x < 64 && node < N) {
            int c = cnt[threadIdx.x];
            nsrc[node] = c > 0 ? rsqrtf((float)c) : 0.f;
        }
    }
}

// ---------------- device-wide exclusive scan (tile = 2048, 2 kernels) ---------

constexpr int SCAN_TILE = 2048;

__global__ __launch_bounds__(256) void k_scan_partial(const int* __restrict__ deg,
                                                      int* __restrict__ tilesum, int n) {
    __shared__ int red[256];
    int base = blockIdx.x * SCAN_TILE;
    int s = 0;
    for (int i = threadIdx.x; i < SCAN_TILE; i += 256) {
        int idx = base + i;
        if (idx < n) s += deg[idx];
    }
    red[threadIdx.x] = s;
    __syncthreads();
    for (int off = 128; off > 0; off >>= 1) {
        if (threadIdx.x < off) red[threadIdx.x] += red[threadIdx.x + off];
        __syncthreads();
    }
    if (threadIdx.x == 0) tilesum[blockIdx.x] = red[0];
}

// R20: each block computes its own exclusive tile base (sum of tilesum[0..bid))
// — replaces the serial single-thread k_scan_tiles dispatch.
__global__ __launch_bounds__(256) void k_scan_final(const int* __restrict__ deg,
                                                    const int* __restrict__ tilesum,
                                                    int* __restrict__ outArr, int n) {
    __shared__ int red[256];
    __shared__ int sbase;
    int s0 = 0;
    for (int i = threadIdx.x; i < (int)blockIdx.x; i += 256) s0 += tilesum[i];
    red[threadIdx.x] = s0;
    __syncthreads();
    for (int off = 128; off > 0; off >>= 1) {
        if (threadIdx.x < off) red[threadIdx.x] += red[threadIdx.x + off];
        __syncthreads();
    }
    if (threadIdx.x == 0) sbase = red[0];
    __syncthreads();

    int base = blockIdx.x * SCAN_TILE;
    int lo = base + threadIdx.x * 8;
    int v[8]; int s = 0;
#pragma unroll
    for (int j = 0; j < 8; j++) {
        int idx = lo + j;
        v[j] = (idx < n) ? deg[idx] : 0;
        s += v[j];
    }
    red[threadIdx.x] = s;
    __syncthreads();
    for (int off = 1; off < 256; off <<= 1) {
        int x = red[threadIdx.x];
        int add = (threadIdx.x >= off) ? red[threadIdx.x - off] : 0;
        __syncthreads();
        red[threadIdx.x] = x + add;
        __syncthreads();
    }
    int excl = sbase + (threadIdx.x ? red[threadIdx.x - 1] : 0);
#pragma unroll
    for (int j = 0; j < 8; j++) {
        int idx = lo + j;
        if (idx < n) outArr[idx] = excl;
        excl += v[j];
    }
}

// ---------------- GEMM: B in LDS, A direct from global (R11/R15 form) ----------
// SRC==0: A = fp32 features -> bf16 hi/lo split, B = bf16 hi/lo, 3 bf16 MFMAs.
// SRC==1: A = fp16 x (single), B = fp16 hi/lo, 2 f16 MFMAs.
// RT=1 only: R6/R7's RT=2 regressed (~+5us/GEMM, suspected VGPR-cliff).
// Writes fp16 h + a ZERO row at h[nrows*DOUT] for masked aggregate slots.

template <int DOUT, int SRC>
__global__ __launch_bounds__(256) void k_gemm_hyb(
        const float* __restrict__ xf, const _Float16* __restrict__ xq,
        const unsigned short* __restrict__ wth, const unsigned short* __restrict__ wtl,
        const float* __restrict__ nsrc, _Float16* __restrict__ h, int nrows) {
    constexpr int NT = DOUT / 16;    // n-tiles per wave (8 or 4), wave owns 16 rows x DOUT
    constexpr int LDK = 72;          // 64 k-half + 8 pad (16B-aligned rows)
    __shared__ unsigned short Bh[DOUT * LDK], Bl[DOUT * LDK];

    int tid = threadIdx.x;
    int lane = tid & 63;
    int wv = tid >> 6;
    int quad = lane >> 4, l16 = lane & 15;
    int r0 = blockIdx.x * 64 + wv * 16;
    int rowA = r0 + l16; if (rowA >= nrows) rowA = nrows - 1;   // clamped load row

    // zero row for the aggregate's masked edge slots
    if (blockIdx.x == 0 && tid < DOUT / 8) {
        f32x4 z = {0.f, 0.f, 0.f, 0.f};
        *(f32x4*)((char*)h + ((size_t)nrows * DOUT + tid * 8) * 2) = z;
    }

    f32x4 acc[NT];
#pragma unroll
    for (int nt = 0; nt < NT; nt++) acc[nt] = (f32x4){0.f, 0.f, 0.f, 0.f};

    for (int kh = 0; kh < 2; kh++) {
        if (kh) __syncthreads();
        // stage B half: DOUT n-rows x 64 k
        for (int i = tid; i < DOUT * 16; i += 256) {
            int n = i >> 4, kb = i & 15;
            int koff = kh * 64 + kb * 4;
            *(ushort4*)&Bh[n * LDK + kb * 4] = *(const ushort4*)&wth[n * 128 + koff];
            *(ushort4*)&Bl[n * LDK + kb * 4] = *(const ushort4*)&wtl[n * 128 + koff];
        }
        __syncthreads();

#pragma unroll
        for (int kq = 0; kq < 2; kq++) {
            int koA = kh * 64 + kq * 32 + quad * 8;   // global k offset for A
            int koB = kq * 32 + quad * 8;             // LDS offset within half
            if (SRC == 0) {
                const float* xp = &xf[(size_t)rowA * 128 + koA];
                f32x4 x0 = *(const f32x4*)xp;
                f32x4 x1 = *(const f32x4*)(xp + 4);
                union { bf16x8 v; unsigned short u[8]; } H, L;
                float xs[8] = {x0[0], x0[1], x0[2], x0[3], x1[0], x1[1], x1[2], x1[3]};
#pragma unroll
                for (int j = 0; j < 8; j++) {
                    H.u[j] = f2bf_rne(xs[j]);
                    L.u[j] = f2bf_rne(xs[j] - bf2f(H.u[j]));
                }
                bf16x8 ah = H.v, al = L.v;
#pragma unroll
                for (int nt = 0; nt < NT; nt++) {
                    int n = nt * 16 + l16;
                    bf16x8 bh = *(const bf16x8*)&Bh[n * LDK + koB];
                    bf16x8 bl = *(const bf16x8*)&Bl[n * LDK + koB];
                    acc[nt] = __builtin_amdgcn_mfma_f32_16x16x32_bf16(ah, bh, acc[nt], 0, 0, 0);
                    acc[nt] = __builtin_amdgcn_mfma_f32_16x16x32_bf16(ah, bl, acc[nt], 0, 0, 0);
                    acc[nt] = __builtin_amdgcn_mfma_f32_16x16x32_bf16(al, bh, acc[nt], 0, 0, 0);
                }
            } else {
                f16x8 aq = *(const f16x8*)&xq[(size_t)rowA * 128 + koA];
#pragma unroll
                for (int nt = 0; nt < NT; nt++) {
                    int n = nt * 16 + l16;
                    f16x8 bh = *(const f16x8*)&Bh[n * LDK + koB];
                    f16x8 bl = *(const f16x8*)&Bl[n * LDK + koB];
                    acc[nt] = __builtin_amdgcn_mfma_f32_16x16x32_f16(aq, bh, acc[nt], 0, 0, 0);
                    acc[nt] = __builtin_amdgcn_mfma_f32_16x16x32_f16(aq, bl, acc[nt], 0, 0, 0);
                }
            }
        }
    }

#pragma unroll
    for (int r = 0; r < 4; r++) {
        int row = r0 + quad * 4 + r;
        if (row < nrows) {
            float nm = nsrc[row];
#pragma unroll
            for (int nt = 0; nt < NT; nt++)
                h[(size_t)row * DOUT + nt * 16 + l16] = (_Float16)(acc[nt][r] * nm);
        }
    }
}

// ---------------- aggregation: 16-lane-group-per-node (R2 form, anchor) -------
// At the ~3.5 TB/s scattered-line ceiling (R0/R2/R3/R4 all converge there).
// colidx reads non-temporal (read-once stream); x/out writes REGULAR.

template <int D, int MODE>
__global__ __launch_bounds__(256) void k_aggregate(const _Float16* __restrict__ h,
                                                   const int* __restrict__ rowptr,
                                                   const int* __restrict__ colidx,
                                                   const float* __restrict__ ndst,
                                                   const float* __restrict__ bias,
                                                   float* __restrict__ out,
                                                   _Float16* __restrict__ oq,
                                                   int n) {
    constexpr int FB = D / 8;              // lanes per node row (16B fp16 each)
    constexpr int GN = 64 / FB;            // nodes per wave
    constexpr int EU = 4;                  // edges in flight per group
    int wid  = (blockIdx.x * 256 + threadIdx.x) >> 6;
    int lane = threadIdx.x & 63;
    int fb = lane & (FB - 1);
    int g  = lane / FB;
    int waveCount = gridDim.x * 4;

    for (int nbase = wid * GN; nbase < n; nbase += waveCount * GN) {
        int node = nbase + g;
        bool vn = node < n;
        int beg = vn ? rowptr[node] : 0;
        int end = vn ? rowptr[node + 1] : 0;
        int m = end - beg;

        int mmax = m;
#pragma unroll
        for (int off = FB; off < 64; off <<= 1) {
            int t = __shfl_xor(mmax, off);
            mmax = mmax > t ? mmax : t;
        }

        float acc[8];
#pragma unroll
        for (int k = 0; k < 8; k++) acc[k] = 0.f;

        int cv = 0;
        for (int j0 = 0; j0 < mmax; j0 += EU) {
            if ((j0 & (FB - 1)) == 0) {
                int idx = beg + j0 + fb;
                cv = __builtin_nontemporal_load(&colidx[idx < end ? idx : 0]);
            }
            int s[EU];
#pragma unroll
            for (int u = 0; u < EU; u++) {
                int j = j0 + u;
                int sv = __shfl(cv, g * FB + (j & (FB - 1)));
                s[u] = j < m ? sv : n;             // row n = zero row
            }
            f16x8 v[EU];
#pragma unroll
            for (int u = 0; u < EU; u++)
                v[u] = *(const f16x8*)&h[(size_t)s[u] * D + fb * 8];
#pragma unroll
            for (int u = 0; u < EU; u++) {
#pragma unroll
                for (int k = 0; k < 8; k++)
                    acc[k] += (float)v[u][k];
            }
        }

        if (vn) {
            float nd = ndst[node];
            float bv[8];
            *(float4*)&bv[0] = ((const float4*)bias)[fb * 2];
            *(float4*)&bv[4] = ((const float4*)bias)[fb * 2 + 1];
            float vv[8];
#pragma unroll
            for (int k = 0; k < 8; k++) vv[k] = acc[k] * nd + bv[k];
            if (MODE == 1) {
                f16x8 q;
#pragma unroll
                for (int k = 0; k < 8; k++)
                    q[k] = (_Float16)fast_tanh(vv[k]);
                *(f16x8*)&oq[(size_t)node * D + fb * 8] = q;
            } else {
                *(float4*)&out[(size_t)node * D + fb * 8] = *(float4*)&vv[0];
                *(float4*)&out[(size_t)node * D + fb * 8 + 4] = *(float4*)&vv[4];
            }
        }
    }
}

// ---------------- host ----------------

extern "C" void kernel_launch(void* const* d_in, const int* in_sizes, int n_in,
                              void* d_out, int out_size, void* d_ws, size_t ws_size,
                              hipStream_t stream) {
    const float* features = (const float*)d_in[0];
    const int* edges      = (const int*)d_in[1];
    const float* W0 = (const float*)d_in[2]; const float* b0 = (const float*)d_in[3];
    const float* W1 = (const float*)d_in[4]; const float* b1 = (const float*)d_in[5];
    const float* W2 = (const float*)d_in[6]; const float* b2 = (const float*)d_in[7];
    const float* W3 = (const float*)d_in[8]; const float* b3 = (const float*)d_in[9];
    float* out = (float*)d_out;

    const int N = in_sizes[0] / 128;
    const int E = in_sizes[1] / 2;
    const int* src = edges;
    const int* dst = edges + E;
    const int K = (N + 63) >> 6;
    const int chunk = (E + CB - 1) / CB;
    const int scanN = K * CB;
    const int n2 = 2 * scanN;
    const int numTiles = (n2 + SCAN_TILE - 1) / SCAN_TILE;
    const size_t dynLds = (size_t)2 * K * sizeof(int);

    char* p = (char*)d_ws;
    _Float16* bufH         = (_Float16*)p;       p += (size_t)N * 128 * 4;  // fp32-sized slot; row N = zero row
    _Float16* xq           = (_Float16*)p;       p += (size_t)(N + 1) * 128 * 2;
    char*     xspare       = p;                  p += (size_t)(N + 1) * 128 * 2;  // transient-sort spill
    int*   rowptr = (int*)p;   p += (((size_t)(N + 1) * 4 + 15) / 16) * 16;
    int*   colidx = (int*)p;   p += (size_t)E * 4;
    float* nsrc   = (float*)p; p += (size_t)N * 4;
    float* ndst   = (float*)p; p += (size_t)N * 4;
    int*   tilesum= (int*)p;   p += (((size_t)(numTiles + 1) * 4 + 15) / 16) * 16;
    unsigned short* wt0h = (unsigned short*)p; p += 16384 * 2;
    unsigned short* wt0l = (unsigned short*)p; p += 16384 * 2;
    unsigned short* wt1h = (unsigned short*)p; p += 16384 * 2;
    unsigned short* wt1l = (unsigned short*)p; p += 16384 * 2;
    unsigned short* wt2h = (unsigned short*)p; p += 16384 * 2;
    unsigned short* wt2l = (unsigned short*)p; p += 16384 * 2;
    unsigned short* wt3h = (unsigned short*)p; p += 8192 * 2;
    unsigned short* wt3l = (unsigned short*)p; p += 8192 * 2;

    // transient counting-sort buffers aliased into xq/xspare region
    char* q = (char*)xq;
    int* sortedAll = (int*)q; q += (size_t)2 * E * 4;
    int* gH        = (int*)q; q += (size_t)n2 * 4;
    int* gHS       = (int*)q; q += (size_t)(n2 + 1) * 4;
    (void)xspare;

    k_prep_hist<<<CB + PREPB, 256, dynLds, stream>>>(src, dst, gH, E, K, scanN, chunk,
                                                     W0, W1, W2, W3,
                                                     wt0h, wt0l, wt1h, wt1l,
                                                     wt2h, wt2l, wt3h, wt3l);
    k_scan_partial<<<numTiles, 256, 0, stream>>>(gH, tilesum, n2);
    k_scan_final<<<numTiles, 256, 0, stream>>>(gH, tilesum, gHS, n2);
    k_bucket_scatter<<<CB, 256, dynLds, stream>>>(src, dst, gHS, sortedAll, E, K, scanN, chunk);
    k_fine<<<2 * K, 256, 0, stream>>>(sortedAll, gHS, rowptr, colidx, nsrc, ndst, E, K, scanN, N);

    int gblk = (N + 63) / 64;
    int ablk128 = (N + 15) / 16;   // 4 waves/block x 4 nodes/wave
    int ablk64  = (N + 31) / 32;   // 4 waves/block x 8 nodes/wave
    k_gemm_hyb<128, 0><<<gblk, 256, 0, stream>>>(features, nullptr, wt0h, wt0l, nsrc, bufH, N);
    k_aggregate<128, 1><<<ablk128, 256, 0, stream>>>(bufH, rowptr, colidx, ndst, b0, nullptr, xq, N);
    k_gemm_hyb<128, 1><<<gblk, 256, 0, stream>>>(nullptr, xq, wt1h, wt1l, nsrc, bufH, N);
    k_aggregate<128, 1><<<ablk128, 256, 0, stream>>>(bufH, rowptr, colidx, ndst, b1, nullptr, xq, N);
    k_gemm_hyb<128, 1><<<gblk, 256, 0, stream>>>(nullptr, xq, wt2h, wt2l, nsrc, bufH, N);
    k_aggregate<128, 1><<<ablk128, 256, 0, stream>>>(bufH, rowptr, colidx, ndst, b2, nullptr, xq, N);
    k_gemm_hyb<64, 1><<<gblk, 256, 0, stream>>>(nullptr, xq, wt3h, wt3l, nsrc, bufH, N);
    k_aggregate<64, 0><<<ablk64, 256, 0, stream>>>(bufH, rowptr, colidx, ndst, b3, out, nullptr, N);
}